// Round 1
// 8083.377 us; speedup vs baseline: 1.0926x; 1.0926x over previous
//
#include <hip/hip_runtime.h>
#include <hip/hip_bf16.h>

#define N_NODES 100000
#define N_EDGES 1600000
#define N_GRAPHS 1000
#define HID 64
#define GRP 10

typedef __attribute__((ext_vector_type(8))) short bf16x8;
typedef __attribute__((ext_vector_type(4))) float f32x4;

// ---------- helpers ----------
__device__ __forceinline__ float bf1(unsigned short u){ union{unsigned int x; float f;} v; v.x = ((unsigned int)u)<<16; return v.f; }
__device__ __forceinline__ float bf_lo(unsigned int u){ union{unsigned int x; float f;} v; v.x = u<<16; return v.f; }
__device__ __forceinline__ float bf_hi(unsigned int u){ union{unsigned int x; float f;} v; v.x = u & 0xFFFF0000u; return v.f; }
__device__ __forceinline__ unsigned short f2bf(float f){
  union{float f; unsigned int i;} v; v.f = f;
  unsigned int r = v.i + 0x7FFFu + ((v.i >> 16) & 1u);
  return (unsigned short)(r >> 16);
}
__device__ __forceinline__ float eluf(float v){ return v > 0.f ? v : expm1f(v); }

// order-preserving float->uint encoding for atomicMax-based segment max
__device__ __forceinline__ unsigned int encf(float f){
  unsigned int u = __float_as_uint(f);
  return (u & 0x80000000u) ? ~u : (u | 0x80000000u);
}
__device__ __forceinline__ float decf(unsigned int u){
  unsigned int b = (u & 0x80000000u) ? (u & 0x7FFFFFFFu) : ~u;
  return __uint_as_float(b);
}

// ---------- weight transpose (f32 -> f32) ----------
struct CvtEnt { const float* s; float* d; int rows; int cols; };
struct CvtArgs { CvtEnt e[16]; int cnt; };

__global__ __launch_bounds__(256) void k_convert(CvtArgs a){
  CvtEnt E = a.e[blockIdx.y];
  int n = E.rows * E.cols;
  for (int i = blockIdx.x*256 + threadIdx.x; i < n; i += gridDim.x*256){
    int r = i / E.cols, c = i % E.cols;
    E.d[(size_t)c*E.rows + r] = E.s[i];
  }
}

// bf16 transposed (and K-padded) weights for the MFMA edge-embedding kernel.
// W1: [50][64] -> W1Tb [64 out][64 k] (k>=50 zero)
// W2a/W2b: [64][64] -> W2Tb* [64 out][64 k]
__global__ __launch_bounds__(256) void k_wprep(const float* __restrict__ W1,
  const float* __restrict__ W2a, const float* __restrict__ W2b,
  unsigned short* __restrict__ W1Tb, unsigned short* __restrict__ W2Tba,
  unsigned short* __restrict__ W2Tbb)
{
  int i = blockIdx.x*256 + threadIdx.x;   // 0..4095
  if (i >= 4096) return;
  int out = i & 63, k = i >> 6;
  int ks = k < 50 ? k : 0;
  unsigned short v1 = f2bf(W1[ks*64 + out]);
  if (k >= 50) v1 = 0;
  W1Tb [out*64 + k] = v1;
  W2Tba[out*64 + k] = f2bf(W2a[k*64 + out]);
  W2Tbb[out*64 + k] = f2bf(W2b[k*64 + out]);
}

// ---------- fused MFMA edge embedding ----------
// e_emb[e,:] = (relu(edge_attr[e,:] @ W1 + b1)) @ W2   (bf16 out)
// 64 rows per block, 4 waves, wave handles 16 rows. 16x16x32 bf16 MFMA.
// A-frag: lane holds A[lane&15][(lane>>4)*8 + i]; B-frag from WT rows (out features).
// C/D: col = lane&15 (out), row = (lane>>4)*4 + reg (edge row)  [measured m89].
__global__ __launch_bounds__(256) void k_edge_emb(
  const float* __restrict__ EA, const unsigned short* __restrict__ W1Tb,
  const float* __restrict__ b1, const unsigned short* __restrict__ W2Tb,
  unsigned short* __restrict__ out, int nE)
{
  __shared__ float ea[64*50];              // 12.8 KB fp32 input tile (reused as out staging)
  __shared__ unsigned short hb[64*72];     // 9.2 KB bf16 hidden tile, pitch 72 (bank-friendly)

  int tid = threadIdx.x;
  int lane = tid & 63;
  int wave = tid >> 6;
  int row16 = lane & 15;
  int kg = lane >> 4;                      // k-group 0..3
  long tile = (long)blockIdx.x * 64;

  // weight fragments (L2-resident)
  bf16x8 w1[4][2], w2[4][2];
  #pragma unroll
  for (int n=0;n<4;n++){
    #pragma unroll
    for (int kk=0;kk<2;kk++){
      w1[n][kk] = *(const bf16x8*)(W1Tb + (n*16+row16)*64 + kk*32 + kg*8);
      w2[n][kk] = *(const bf16x8*)(W2Tb + (n*16+row16)*64 + kk*32 + kg*8);
    }
  }
  float bias[4];
  #pragma unroll
  for (int n=0;n<4;n++) bias[n] = b1[n*16+row16];

  // stage edge_attr tile (64 rows x 50 f32, flat coalesced)
  const float* g = EA + tile*50;
  for (int i = tid; i < 3200; i += 256) ea[i] = g[i];
  __syncthreads();

  // stage1 A-frags (fp32 -> bf16 in-register)
  int r = wave*16 + row16;
  bf16x8 a0, a1;
  {
    const float* p = ea + r*50;
    #pragma unroll
    for (int i=0;i<8;i++) ((short*)&a0)[i] = (short)f2bf(p[kg*8+i]);
    #pragma unroll
    for (int i=0;i<8;i++){
      int k = 32 + kg*8 + i;
      float v = (k < 50) ? p[k] : 0.f;
      ((short*)&a1)[i] = (short)((k < 50) ? f2bf(v) : (unsigned short)0);
    }
  }
  f32x4 c[4];
  #pragma unroll
  for (int n=0;n<4;n++){
    f32x4 acc = {0.f,0.f,0.f,0.f};
    acc = __builtin_amdgcn_mfma_f32_16x16x32_bf16(a0, w1[n][0], acc, 0,0,0);
    acc = __builtin_amdgcn_mfma_f32_16x16x32_bf16(a1, w1[n][1], acc, 0,0,0);
    c[n] = acc;
  }
  // bias + relu, h -> LDS (bf16). row = wave*16 + kg*4 + q, col = n*16 + row16
  #pragma unroll
  for (int n=0;n<4;n++){
    #pragma unroll
    for (int q=0;q<4;q++){
      float v = fmaxf(c[n][q] + bias[n], 0.f);
      hb[(wave*16 + kg*4 + q)*72 + n*16 + row16] = f2bf(v);
    }
  }
  __syncthreads();

  // stage2 A-frags from LDS
  bf16x8 ha, hc;
  {
    const unsigned short* p = hb + r*72;
    ha = *(const bf16x8*)(p + kg*8);
    hc = *(const bf16x8*)(p + 32 + kg*8);
  }
  f32x4 d[4];
  #pragma unroll
  for (int n=0;n<4;n++){
    f32x4 acc = {0.f,0.f,0.f,0.f};
    acc = __builtin_amdgcn_mfma_f32_16x16x32_bf16(ha, w2[n][0], acc, 0,0,0);
    acc = __builtin_amdgcn_mfma_f32_16x16x32_bf16(hc, w2[n][1], acc, 0,0,0);
    d[n] = acc;
  }
  // stage out tile in LDS (reuse ea region; all ea reads completed before barrier 2)
  unsigned short* ob = (unsigned short*)ea;   // pitch 72, 64*72 shorts fits in 3200 floats
  #pragma unroll
  for (int n=0;n<4;n++){
    #pragma unroll
    for (int q=0;q<4;q++)
      ob[(wave*16 + kg*4 + q)*72 + n*16 + row16] = f2bf(d[n][q]);
  }
  __syncthreads();

  // coalesced store: 64 rows x 128B, thread t handles 32B
  {
    int rr = tid >> 2, q = tid & 3;
    const uint4* s = (const uint4*)(ob + rr*72 + q*16);
    uint4 v0 = s[0], v1 = s[1];
    uint4* gp = (uint4*)(out + (tile + rr)*64 + q*16);
    gp[0] = v0; gp[1] = v1;
  }
}

// ---------- generic linear: out[n,0..63] = act(A[n,:] @ W + b) ----------
template<int K, int RELU, int INBF, int OUTBF, int HASB>
__global__ __launch_bounds__(256) void k_linear64(const void* Ap,
    const float* __restrict__ WT, const float* __restrict__ bias, void* Op, int N)
{
  int n = blockIdx.x*256 + threadIdx.x;
  if (n >= N) return;
  float a[K];
  if constexpr (INBF){
    const unsigned int* p = (const unsigned int*)((const unsigned short*)Ap + (size_t)n*K);
    #pragma unroll
    for (int i=0;i<K/2;i++){ unsigned int u=p[i]; a[2*i]=bf_lo(u); a[2*i+1]=bf_hi(u); }
  } else if constexpr (K % 4 == 0){
    const float4* p = (const float4*)((const float*)Ap + (size_t)n*K);
    #pragma unroll
    for (int i=0;i<K/4;i++){ float4 v=p[i]; a[4*i]=v.x; a[4*i+1]=v.y; a[4*i+2]=v.z; a[4*i+3]=v.w; }
  } else {
    const float2* p = (const float2*)((const float*)Ap + (size_t)n*K);
    #pragma unroll
    for (int i=0;i<K/2;i++){ float2 v=p[i]; a[2*i]=v.x; a[2*i+1]=v.y; }
  }
  for (int c=0;c<64;c+=4){
    float s0 = HASB ? bias[c+0] : 0.f;
    float s1 = HASB ? bias[c+1] : 0.f;
    float s2 = HASB ? bias[c+2] : 0.f;
    float s3 = HASB ? bias[c+3] : 0.f;
    const float* w = WT + (size_t)c*K;
    #pragma unroll
    for (int k=0;k<K;k++){
      float av = a[k];
      s0 = fmaf(av, w[k],     s0);
      s1 = fmaf(av, w[K+k],   s1);
      s2 = fmaf(av, w[2*K+k], s2);
      s3 = fmaf(av, w[3*K+k], s3);
    }
    if (RELU){ s0=fmaxf(s0,0.f); s1=fmaxf(s1,0.f); s2=fmaxf(s2,0.f); s3=fmaxf(s3,0.f); }
    if constexpr (OUTBF){
      uint2 uu;
      uu.x = ((unsigned int)f2bf(s1)<<16) | f2bf(s0);
      uu.y = ((unsigned int)f2bf(s3)<<16) | f2bf(s2);
      *(uint2*)((unsigned short*)Op + (size_t)n*64 + c) = uu;
    } else {
      float4 r; r.x=s0; r.y=s1; r.z=s2; r.w=s3;
      *(float4*)((float*)Op + (size_t)n*64 + c) = r;
    }
  }
}

// ---------- GATv2 edge passes ----------
__global__ __launch_bounds__(256) void k_edge_logit(
  const int* __restrict__ src, const int* __restrict__ dst,
  const float* __restrict__ xl, const float* __restrict__ xr,
  const unsigned short* __restrict__ emb, const float* __restrict__ att,
  float* __restrict__ logits, unsigned int* __restrict__ nmax, int nE)
{
  int lane = threadIdx.x & 63;
  float av = att[lane];
  int wid = (blockIdx.x*256 + threadIdx.x) >> 6;
  int nw  = (gridDim.x*256) >> 6;
  for (int e = wid; e < nE; e += nw){
    int sN = src ? src[e] : e;
    int dN = dst[e];
    float v = xl[(size_t)sN*64 + lane] + xr[(size_t)dN*64 + lane];
    if (emb) v += bf1(emb[(size_t)e*64 + lane]);
    v = v > 0.f ? v : 0.01f*v;
    float p = v * av;
    #pragma unroll
    for (int o=32;o;o>>=1) p += __shfl_xor(p, o, 64);
    if (lane == 0){
      logits[e] = p;
      atomicMax(nmax + dN, encf(p));
    }
  }
}

// fused: w = exp(logit - max); nsum += w; agg += w * xl[src]  (normalize later in gru)
__global__ __launch_bounds__(256) void k_edge_expagg(
  const int* __restrict__ src, const int* __restrict__ dst,
  const float* __restrict__ xl, const float* __restrict__ logits,
  const unsigned int* __restrict__ nmax, float* __restrict__ nsum,
  float* __restrict__ agg, int nE)
{
  int lane = threadIdx.x & 63;
  int wid = (blockIdx.x*256 + threadIdx.x) >> 6;
  int nw  = (gridDim.x*256) >> 6;
  for (int e = wid; e < nE; e += nw){
    int sN = src ? src[e] : e;
    int dN = dst[e];
    float w = expf(logits[e] - decf(nmax[dN]));
    if (lane == 0) atomicAdd(nsum + dN, w);
    atomicAdd(agg + (size_t)dN*64 + lane, xl[(size_t)sN*64 + lane] * w);
  }
}

// ---------- GRU (h = elu(agg/nsum + gat_bias); writes relu(gru) in-place into x) ----------
__global__ __launch_bounds__(256) void k_gru(const float* __restrict__ agg,
  const float* __restrict__ nsum, const float* __restrict__ gatb, float* x,
  const float* __restrict__ Wih, const float* __restrict__ Whh,
  const float* __restrict__ bih, const float* __restrict__ bhh, int N)
{
  int n = blockIdx.x*256 + threadIdx.x;
  if (n >= N) return;
  float h[64], xv[64];
  float inv = 1.f/(nsum[n] + 1e-16f);
  const float4* pa = (const float4*)(agg + (size_t)n*64);
  const float4* px = (const float4*)(x   + (size_t)n*64);
  #pragma unroll
  for (int i=0;i<16;i++){
    float4 avv = pa[i]; float4 xx = px[i];
    h[4*i+0]=eluf(avv.x*inv + gatb[4*i+0]);
    h[4*i+1]=eluf(avv.y*inv + gatb[4*i+1]);
    h[4*i+2]=eluf(avv.z*inv + gatb[4*i+2]);
    h[4*i+3]=eluf(avv.w*inv + gatb[4*i+3]);
    xv[4*i+0]=xx.x; xv[4*i+1]=xx.y; xv[4*i+2]=xx.z; xv[4*i+3]=xx.w;
  }
  for (int c=0;c<64;c++){
    float ir=bih[c], iz=bih[64+c], in2=bih[128+c];
    float hr=bhh[c], hz=bhh[64+c], hn=bhh[128+c];
    const float* wi = Wih + (size_t)c*64;
    const float* wh = Whh + (size_t)c*64;
    #pragma unroll
    for (int k=0;k<64;k++){
      float hk = h[k], xk = xv[k];
      ir  = fmaf(hk, wi[k],      ir);
      iz  = fmaf(hk, wi[4096+k], iz);
      in2 = fmaf(hk, wi[8192+k], in2);
      hr  = fmaf(xk, wh[k],      hr);
      hz  = fmaf(xk, wh[4096+k], hz);
      hn  = fmaf(xk, wh[8192+k], hn);
    }
    float r = 1.f/(1.f + expf(-(ir+hr)));
    float z = 1.f/(1.f + expf(-(iz+hz)));
    float nn = tanhf(in2 + r*hn);
    float o = (1.f - z)*nn + z*xv[c];
    x[(size_t)n*64 + c] = fmaxf(o, 0.f);
  }
}

// ---------- DiffGroupNorm ----------
__global__ __launch_bounds__(256) void k_dgn_s(const float* __restrict__ x,
  const float* __restrict__ WT /*10x64*/, const float* __restrict__ b,
  float* __restrict__ s, int N)
{
  int n = blockIdx.x*256 + threadIdx.x;
  if (n >= N) return;
  float a[64];
  const float4* p = (const float4*)(x + (size_t)n*64);
  #pragma unroll
  for (int i=0;i<16;i++){ float4 v=p[i]; a[4*i]=v.x; a[4*i+1]=v.y; a[4*i+2]=v.z; a[4*i+3]=v.w; }
  float lg[10];
  #pragma unroll
  for (int g=0; g<10; g++){
    float acc = b[g];
    const float* w = WT + (size_t)g*64;
    #pragma unroll
    for (int k=0;k<64;k++) acc = fmaf(a[k], w[k], acc);
    lg[g] = acc;
  }
  float m = lg[0];
  #pragma unroll
  for (int g=1;g<10;g++) m = fmaxf(m, lg[g]);
  float e[10], sum = 0.f;
  #pragma unroll
  for (int g=0;g<10;g++){ e[g] = expf(lg[g]-m); sum += e[g]; }
  float inv = 1.f/sum;
  #pragma unroll
  for (int g=0;g<10;g++) s[(size_t)n*10+g] = e[g]*inv;
}

__global__ __launch_bounds__(640) void k_dgn_stats(const float* __restrict__ s,
  const float* __restrict__ x, float* cs, float* cs2, int N)
{
  int g = threadIdx.x >> 6, f = threadIdx.x & 63;
  int per = (N + gridDim.x - 1) / gridDim.x;
  int n0 = blockIdx.x * per;
  int n1 = min(N, n0 + per);
  float a = 0.f, a2 = 0.f;
  for (int n = n0; n < n1; n++){
    float y = s[(size_t)n*10+g] * x[(size_t)n*64+f];
    a += y; a2 += y*y;
  }
  atomicAdd(&cs [g*64+f], a);
  atomicAdd(&cs2[g*64+f], a2);
}

__global__ void k_dgn_final(const float* cs, const float* cs2,
  const float* __restrict__ bw, const float* __restrict__ bb,
  float* scale, float* shiftsum, int N)
{
  __shared__ float sh[640];
  int i = threadIdx.x;
  float invN = 1.f / (float)N;
  float mean = cs[i]*invN;
  float var  = cs2[i]*invN - mean*mean;
  float sc = bw[i] / sqrtf(var + 1e-5f);
  scale[i] = sc;
  sh[i] = bb[i] - mean*sc;
  __syncthreads();
  if (i < 64){
    float t = 0.f;
    #pragma unroll
    for (int g=0;g<10;g++) t += sh[g*64+i];
    shiftsum[i] = t;
  }
}

__global__ __launch_bounds__(256) void k_dgn_apply(float* x,
  const float* __restrict__ s, const float* __restrict__ scale,
  const float* __restrict__ shiftsum, int N)
{
  int idx = blockIdx.x*256 + threadIdx.x;
  if (idx >= N*64) return;
  int n = idx >> 6, f = idx & 63;
  float ss = 0.f;
  #pragma unroll
  for (int g=0; g<10; g++) ss = fmaf(s[(size_t)n*10+g], scale[g*64+f], ss);
  float xvv = x[idx];
  x[idx] = xvv + 0.01f*(xvv*ss + shiftsum[f]);
}

// ---------- readout ----------
__global__ __launch_bounds__(256) void k_segsum(const float* __restrict__ x,
  const int* __restrict__ batch, float* __restrict__ gout)
{
  int idx = blockIdx.x*256 + threadIdx.x;
  if (idx >= N_NODES*64) return;
  int n = idx >> 6, c = idx & 63;
  atomicAdd(gout + (size_t)batch[n]*64 + c, x[idx]);
}

__global__ __launch_bounds__(256) void k_relu(float* p, int n){
  int i = blockIdx.x*256 + threadIdx.x;
  if (i < n) p[i] = fmaxf(p[i], 0.f);
}

__global__ __launch_bounds__(256) void k_head(const float* __restrict__ y,
  const float* __restrict__ w, const float* __restrict__ b,
  float* __restrict__ out, int N)
{
  int n = blockIdx.x*256 + threadIdx.x;
  if (n >= N) return;
  float acc = b[0];
  const float4* p = (const float4*)(y + (size_t)n*64);
  #pragma unroll
  for (int i=0;i<16;i++){
    float4 v = p[i];
    acc = fmaf(v.x, w[4*i+0], acc);
    acc = fmaf(v.y, w[4*i+1], acc);
    acc = fmaf(v.z, w[4*i+2], acc);
    acc = fmaf(v.w, w[4*i+3], acc);
  }
  out[n] = acc;
}

// ---------- host ----------
extern "C" void kernel_launch(void* const* d_in, const int* in_sizes, int n_in,
                              void* d_out, int out_size, void* d_ws, size_t ws_size,
                              hipStream_t stream) {
  (void)in_sizes; (void)n_in; (void)out_size; (void)ws_size;

  // ----- workspace layout -----
  char* base = (char*)d_ws; size_t off = 0;
  auto A = [&](size_t bytes)->void*{ void* p = base + off; off += (bytes + 255) & ~(size_t)255; return p; };
  unsigned short* e_emb = (unsigned short*)A((size_t)N_EDGES*64*2);   // bf16 e_emb
  float* xbuf   = (float*)A((size_t)N_NODES*64*4);
  float* xl     = (float*)A((size_t)N_NODES*64*4);
  float* xr     = (float*)A((size_t)N_NODES*64*4);
  float* agg    = (float*)A((size_t)N_NODES*64*4);
  float* logits = (float*)A((size_t)N_EDGES*4);
  unsigned int* nmax = (unsigned int*)A((size_t)N_NODES*4);
  float* nsum   = (float*)A((size_t)N_NODES*4);
  float* sbuf   = (float*)A((size_t)N_NODES*10*4);
  float* gout   = (float*)A((size_t)N_GRAPHS*64*4);
  float* ybuf   = (float*)A((size_t)N_GRAPHS*64*4);
  float* ybuf2  = (float*)A((size_t)N_GRAPHS*64*4);
  float* colsum = (float*)A(2*640*4); float* colsumsq = colsum + 640;
  float* scale  = (float*)A((640+64)*4); float* shiftsum = scale + 640;
  unsigned short* W1Tb  = (unsigned short*)A(4096*2);
  unsigned short* W2Tb0 = (unsigned short*)A(4096*2);
  unsigned short* W2Tb1 = (unsigned short*)A(4096*2);
  float* wf     = (float*)A(60000*4);
  size_t wo = 0;
  auto W = [&](size_t n)->float*{ float* p = wf + wo; wo += n; return p; };

  float* pre_nWT = W(64*92);
  float* WlT[2] = {W(4096), W(4096)};
  float* WrT[2] = {W(4096), W(4096)};
  float* gnWT[2] = {W(640), W(640)};
  float* gWlT = W(4096);
  float* gWrT = W(4096);
  float* ggnWT = W(640);
  float* postWT[2] = {W(4096), W(4096)};

  const float* F[48];
  for (int i=0;i<41;i++) F[i] = (const float*)d_in[i];

  // ----- transpose table -----
  CvtArgs ca; ca.cnt = 0;
  auto addT = [&](const float* s, float* d, int r, int c){
    ca.e[ca.cnt].s=s; ca.e[ca.cnt].d=d; ca.e[ca.cnt].rows=r; ca.e[ca.cnt].cols=c; ca.cnt++; };

  addT(F[4],  pre_nWT, 92, 64);
  for (int l=0;l<2;l++) addT(F[8]  + l*4096, WlT[l], 64, 64);
  for (int l=0;l<2;l++) addT(F[10] + l*4096, WrT[l], 64, 64);
  for (int l=0;l<2;l++) addT(F[19] + l*640,  gnWT[l], 64, 10);
  addT(F[23], gWlT, 64, 64);
  addT(F[25], gWrT, 64, 64);
  addT(F[33], ggnWT, 64, 10);
  for (int l=0;l<2;l++) addT(F[37] + l*4096, postWT[l], 64, 64);

  const int* src   = (const int*)d_in[1];
  const int* dst   = src + N_EDGES;
  const int* batch = (const int*)d_in[3];

  const int NBn = (N_NODES + 255)/256;    // 391
  const int NBg = (N_GRAPHS + 255)/256;   // 4
  const int NBa = (N_NODES*64)/256;       // 25000
  const int NBemb = N_EDGES/64;           // 25000

  k_convert<<<dim3(24, ca.cnt), 256, 0, stream>>>(ca);
  k_wprep<<<16,256,0,stream>>>(F[6], F[12], F[12]+4096, W1Tb, W2Tb0, W2Tb1);

  // x = relu(x_in @ pre_nW + pre_nb)
  k_linear64<92,1,0,0,1><<<NBn,256,0,stream>>>(F[0], pre_nWT, F[5], xbuf, N_NODES);

  for (int l=0; l<2; l++){
    // e_emb = relu(edge_attr @ pre_eW + pre_eb) @ We[l]   (fused MFMA, bf16)
    k_edge_emb<<<NBemb,256,0,stream>>>(F[2], W1Tb, F[7], (l==0)?W2Tb0:W2Tb1, e_emb, N_EDGES);

    for (int t=0; t<2; t++){
      k_linear64<64,0,0,0,1><<<NBn,256,0,stream>>>(xbuf, WlT[l], F[9]  + l*64, xl, N_NODES);
      k_linear64<64,0,0,0,1><<<NBn,256,0,stream>>>(xbuf, WrT[l], F[11] + l*64, xr, N_NODES);
      hipMemsetAsync(nmax, 0, (size_t)N_NODES*4, stream);
      hipMemsetAsync(nsum, 0, (size_t)N_NODES*4, stream);
      hipMemsetAsync(agg,  0, (size_t)N_NODES*64*4, stream);
      k_edge_logit<<<4096,256,0,stream>>>(src, dst, xl, xr, e_emb, F[13] + l*64, logits, nmax, N_EDGES);
      k_edge_expagg<<<4096,256,0,stream>>>(src, dst, xl, logits, nmax, nsum, agg, N_EDGES);
      k_gru<<<NBn,256,0,stream>>>(agg, nsum, F[14] + l*64, xbuf, F[15] + l*12288, F[16] + l*12288,
                                  F[17] + l*192, F[18] + l*192, N_NODES);
    }
    hipMemsetAsync(colsum, 0, 2*640*4, stream);
    k_dgn_s<<<NBn,256,0,stream>>>(xbuf, gnWT[l], F[20] + l*10, sbuf, N_NODES);
    k_dgn_stats<<<128,640,0,stream>>>(sbuf, xbuf, colsum, colsumsq, N_NODES);
    k_dgn_final<<<1,640,0,stream>>>(colsum, colsumsq, F[21] + l*640, F[22] + l*640, scale, shiftsum, N_NODES);
    k_dgn_apply<<<NBa,256,0,stream>>>(xbuf, sbuf, scale, shiftsum, N_NODES);
  }

  // readout: out = relu(segment_sum(x, batch))
  hipMemsetAsync(gout, 0, (size_t)N_GRAPHS*64*4, stream);
  k_segsum<<<NBa,256,0,stream>>>(xbuf, batch, gout);
  k_relu<<<(N_GRAPHS*64+255)/256,256,0,stream>>>(gout, N_GRAPHS*64);

  // xl_g fixed across both timesteps (x doesn't change here)
  k_linear64<64,0,0,0,1><<<NBn,256,0,stream>>>(xbuf, gWlT, F[24], xl, N_NODES);
  for (int t=0; t<2; t++){
    k_linear64<64,0,0,0,1><<<NBg,256,0,stream>>>(gout, gWrT, F[26], xr, N_GRAPHS);
    hipMemsetAsync(nmax, 0, (size_t)N_GRAPHS*4, stream);
    hipMemsetAsync(nsum, 0, (size_t)N_GRAPHS*4, stream);
    hipMemsetAsync(agg,  0, (size_t)N_GRAPHS*64*4, stream);
    k_edge_logit<<<1024,256,0,stream>>>(nullptr, batch, xl, xr, nullptr, F[27], logits, nmax, N_NODES);
    k_edge_expagg<<<1024,256,0,stream>>>(nullptr, batch, xl, logits, nmax, nsum, agg, N_NODES);
    k_gru<<<NBg,256,0,stream>>>(agg, nsum, F[28], gout, F[29], F[30], F[31], F[32], N_GRAPHS);
  }

  hipMemsetAsync(colsum, 0, 2*640*4, stream);
  k_dgn_s<<<NBg,256,0,stream>>>(gout, ggnWT, F[34], sbuf, N_GRAPHS);
  k_dgn_stats<<<8,640,0,stream>>>(sbuf, gout, colsum, colsumsq, N_GRAPHS);
  k_dgn_final<<<1,640,0,stream>>>(colsum, colsumsq, F[35], F[36], scale, shiftsum, N_GRAPHS);
  k_dgn_apply<<<(N_GRAPHS*64+255)/256,256,0,stream>>>(gout, sbuf, scale, shiftsum, N_GRAPHS);

  // post MLP + head
  k_linear64<64,1,0,0,1><<<NBg,256,0,stream>>>(gout, postWT[0], F[38],      ybuf,  N_GRAPHS);
  k_linear64<64,1,0,0,1><<<NBg,256,0,stream>>>(ybuf, postWT[1], F[38] + 64, ybuf2, N_GRAPHS);
  k_head<<<NBg,256,0,stream>>>(ybuf2, F[39], F[40], (float*)d_out, N_GRAPHS);
}

// Round 3
// 5751.356 us; speedup vs baseline: 1.5356x; 1.4055x over previous
//
#include <hip/hip_runtime.h>
#include <hip/hip_bf16.h>

#define N_NODES 100000
#define N_EDGES 1600000
#define N_GRAPHS 1000
#define HID 64
#define GRP 10

typedef __attribute__((ext_vector_type(8))) short bf16x8;
typedef __attribute__((ext_vector_type(4))) float f32x4;

// ---------- helpers ----------
__device__ __forceinline__ float bf1(unsigned short u){ union{unsigned int x; float f;} v; v.x = ((unsigned int)u)<<16; return v.f; }
__device__ __forceinline__ float bf_lo(unsigned int u){ union{unsigned int x; float f;} v; v.x = u<<16; return v.f; }
__device__ __forceinline__ float bf_hi(unsigned int u){ union{unsigned int x; float f;} v; v.x = u & 0xFFFF0000u; return v.f; }
__device__ __forceinline__ unsigned short f2bf(float f){
  union{float f; unsigned int i;} v; v.f = f;
  unsigned int r = v.i + 0x7FFFu + ((v.i >> 16) & 1u);
  return (unsigned short)(r >> 16);
}
__device__ __forceinline__ float eluf(float v){ return v > 0.f ? v : expm1f(v); }

// ---------- weight transpose (f32 -> f32) ----------
struct CvtEnt { const float* s; float* d; int rows; int cols; };
struct CvtArgs { CvtEnt e[16]; int cnt; };

__global__ __launch_bounds__(256) void k_convert(CvtArgs a){
  CvtEnt E = a.e[blockIdx.y];
  int n = E.rows * E.cols;
  for (int i = blockIdx.x*256 + threadIdx.x; i < n; i += gridDim.x*256){
    int r = i / E.cols, c = i % E.cols;
    E.d[(size_t)c*E.rows + r] = E.s[i];
  }
}

// bf16 transposed (and K-padded) weights for the MFMA edge-embedding kernel.
__global__ __launch_bounds__(256) void k_wprep(const float* __restrict__ W1,
  const float* __restrict__ W2a, const float* __restrict__ W2b,
  unsigned short* __restrict__ W1Tb, unsigned short* __restrict__ W2Tba,
  unsigned short* __restrict__ W2Tbb)
{
  int i = blockIdx.x*256 + threadIdx.x;   // 0..4095
  if (i >= 4096) return;
  int out = i & 63, k = i >> 6;
  int ks = k < 50 ? k : 0;
  unsigned short v1 = f2bf(W1[ks*64 + out]);
  if (k >= 50) v1 = 0;
  W1Tb [out*64 + k] = v1;
  W2Tba[out*64 + k] = f2bf(W2a[k*64 + out]);
  W2Tbb[out*64 + k] = f2bf(W2b[k*64 + out]);
}

// ---------- CSR build: histogram -> scan -> scatter ----------
__global__ __launch_bounds__(256) void k_hist(const int* __restrict__ dst, int* __restrict__ cnt){
  for (int e = blockIdx.x*256 + threadIdx.x; e < N_EDGES; e += gridDim.x*256)
    atomicAdd(cnt + dst[e], 1);
}

__global__ __launch_bounds__(256) void k_scan1(const int* __restrict__ cnt,
  int* __restrict__ excl, int* __restrict__ bsum, int N)
{
  __shared__ int sh[256];
  int t = threadIdx.x;
  int i = blockIdx.x*256 + t;
  int v = (i < N) ? cnt[i] : 0;
  sh[t] = v;
  __syncthreads();
  #pragma unroll
  for (int o=1;o<256;o<<=1){
    int x = (t>=o) ? sh[t-o] : 0;
    __syncthreads();
    sh[t] += x;
    __syncthreads();
  }
  if (i < N) excl[i] = sh[t] - v;
  if (t == 255) bsum[blockIdx.x] = sh[255];
}

__global__ __launch_bounds__(512) void k_scan2(const int* __restrict__ bsum,
  int* __restrict__ bo, int NB)
{
  __shared__ int sh[512];
  int t = threadIdx.x;
  int v = (t < NB) ? bsum[t] : 0;
  sh[t] = v;
  __syncthreads();
  #pragma unroll
  for (int o=1;o<512;o<<=1){
    int x = (t>=o) ? sh[t-o] : 0;
    __syncthreads();
    sh[t] += x;
    __syncthreads();
  }
  if (t < NB) bo[t] = sh[t] - v;
}

__global__ __launch_bounds__(256) void k_scan3(int* __restrict__ segoff,
  const int* __restrict__ bo, int* __restrict__ cursor, int N)
{
  int i = blockIdx.x*256 + threadIdx.x;
  if (i >= N) return;
  int v = segoff[i] + bo[i>>8];
  segoff[i] = v;
  cursor[i] = v;
  if (i == 0) segoff[N] = N_EDGES;
}

__global__ __launch_bounds__(256) void k_scatter(const int* __restrict__ src,
  const int* __restrict__ dst, int* __restrict__ cursor,
  int* __restrict__ srcp, int* __restrict__ perm)
{
  for (int e = blockIdx.x*256 + threadIdx.x; e < N_EDGES; e += gridDim.x*256){
    int d = dst[e];
    int pos = atomicAdd(cursor + d, 1);
    srcp[pos] = src[e];
    perm[pos] = e;
  }
}

// graph segment offsets from sorted batch array
__global__ __launch_bounds__(256) void k_goff(const int* __restrict__ batch, int* __restrict__ goff){
  for (int n = blockIdx.x*256 + threadIdx.x; n < N_NODES; n += gridDim.x*256){
    int b = batch[n];
    int prev = (n==0) ? -1 : batch[n-1];
    for (int g = prev+1; g <= b; g++) goff[g] = n;
    if (n == N_NODES-1){ for (int g=b+1; g<=N_GRAPHS; g++) goff[g] = N_NODES; }
  }
}

// ---------- fused MFMA edge embedding (gathers rows via perm, writes sorted order) ----------
__global__ __launch_bounds__(256) void k_edge_emb(
  const float* __restrict__ EA, const int* __restrict__ perm,
  const unsigned short* __restrict__ W1Tb,
  const float* __restrict__ b1, const unsigned short* __restrict__ W2Tb,
  unsigned short* __restrict__ out, int nE)
{
  __shared__ float ea[64*50];              // fp32 input tile (reused as out staging)
  __shared__ unsigned short hb[64*72];     // bf16 hidden tile, pitch 72
  __shared__ int prm[64];

  int tid = threadIdx.x;
  int lane = tid & 63;
  int wave = tid >> 6;
  int row16 = lane & 15;
  int kg = lane >> 4;                      // k-group 0..3
  long tile = (long)blockIdx.x * 64;

  // weight fragments (L2-resident)
  bf16x8 w1[4][2], w2[4][2];
  #pragma unroll
  for (int n=0;n<4;n++){
    #pragma unroll
    for (int kk=0;kk<2;kk++){
      w1[n][kk] = *(const bf16x8*)(W1Tb + (n*16+row16)*64 + kk*32 + kg*8);
      w2[n][kk] = *(const bf16x8*)(W2Tb + (n*16+row16)*64 + kk*32 + kg*8);
    }
  }
  float bias[4];
  #pragma unroll
  for (int n=0;n<4;n++) bias[n] = b1[n*16+row16];

  if (tid < 64) prm[tid] = perm[tile + tid];
  __syncthreads();

  // stage edge_attr tile (64 permuted rows x 50 f32)
  for (int i = tid; i < 3200; i += 256)
    ea[i] = EA[(size_t)prm[i/50]*50 + (i%50)];
  __syncthreads();

  // stage1 A-frags (fp32 -> bf16 in-register)
  int r = wave*16 + row16;
  bf16x8 a0, a1;
  {
    const float* p = ea + r*50;
    #pragma unroll
    for (int i=0;i<8;i++) ((short*)&a0)[i] = (short)f2bf(p[kg*8+i]);
    #pragma unroll
    for (int i=0;i<8;i++){
      int k = 32 + kg*8 + i;
      ((short*)&a1)[i] = (short)((k < 50) ? f2bf(p[k]) : (unsigned short)0);
    }
  }
  f32x4 c[4];
  #pragma unroll
  for (int n=0;n<4;n++){
    f32x4 acc = {0.f,0.f,0.f,0.f};
    acc = __builtin_amdgcn_mfma_f32_16x16x32_bf16(a0, w1[n][0], acc, 0,0,0);
    acc = __builtin_amdgcn_mfma_f32_16x16x32_bf16(a1, w1[n][1], acc, 0,0,0);
    c[n] = acc;
  }
  // bias + relu, h -> LDS (bf16)
  #pragma unroll
  for (int n=0;n<4;n++){
    #pragma unroll
    for (int q=0;q<4;q++){
      float v = fmaxf(c[n][q] + bias[n], 0.f);
      hb[(wave*16 + kg*4 + q)*72 + n*16 + row16] = f2bf(v);
    }
  }
  __syncthreads();

  // stage2 A-frags from LDS
  bf16x8 ha, hc;
  {
    const unsigned short* p = hb + r*72;
    ha = *(const bf16x8*)(p + kg*8);
    hc = *(const bf16x8*)(p + 32 + kg*8);
  }
  f32x4 d[4];
  #pragma unroll
  for (int n=0;n<4;n++){
    f32x4 acc = {0.f,0.f,0.f,0.f};
    acc = __builtin_amdgcn_mfma_f32_16x16x32_bf16(ha, w2[n][0], acc, 0,0,0);
    acc = __builtin_amdgcn_mfma_f32_16x16x32_bf16(hc, w2[n][1], acc, 0,0,0);
    d[n] = acc;
  }
  __syncthreads();
  // stage out tile in LDS (reuse ea region)
  unsigned short* ob = (unsigned short*)ea;
  #pragma unroll
  for (int n=0;n<4;n++){
    #pragma unroll
    for (int q=0;q<4;q++)
      ob[(wave*16 + kg*4 + q)*72 + n*16 + row16] = f2bf(d[n][q]);
  }
  __syncthreads();

  // coalesced store: 64 rows x 128B, thread t handles 32B
  {
    int rr = tid >> 2, q = tid & 3;
    const uint4* s = (const uint4*)(ob + rr*72 + q*16);
    uint4 v0 = s[0], v1 = s[1];
    uint4* gp = (uint4*)(out + (tile + rr)*64 + q*16);
    gp[0] = v0; gp[1] = v1;
  }
}

// ---------- generic linear: out[n,0..63] = act(A[n,:] @ W + b) ----------
template<int K, int RELU, int INBF, int OUTBF, int HASB>
__global__ __launch_bounds__(256) void k_linear64(const void* Ap,
    const float* __restrict__ WT, const float* __restrict__ bias, void* Op, int N)
{
  int n = blockIdx.x*256 + threadIdx.x;
  if (n >= N) return;
  float a[K];
  if constexpr (INBF){
    const unsigned int* p = (const unsigned int*)((const unsigned short*)Ap + (size_t)n*K);
    #pragma unroll
    for (int i=0;i<K/2;i++){ unsigned int u=p[i]; a[2*i]=bf_lo(u); a[2*i+1]=bf_hi(u); }
  } else if constexpr (K % 4 == 0){
    const float4* p = (const float4*)((const float*)Ap + (size_t)n*K);
    #pragma unroll
    for (int i=0;i<K/4;i++){ float4 v=p[i]; a[4*i]=v.x; a[4*i+1]=v.y; a[4*i+2]=v.z; a[4*i+3]=v.w; }
  } else {
    const float2* p = (const float2*)((const float*)Ap + (size_t)n*K);
    #pragma unroll
    for (int i=0;i<K/2;i++){ float2 v=p[i]; a[2*i]=v.x; a[2*i+1]=v.y; }
  }
  for (int c=0;c<64;c+=4){
    float s0 = HASB ? bias[c+0] : 0.f;
    float s1 = HASB ? bias[c+1] : 0.f;
    float s2 = HASB ? bias[c+2] : 0.f;
    float s3 = HASB ? bias[c+3] : 0.f;
    const float* w = WT + (size_t)c*K;
    #pragma unroll
    for (int k=0;k<K;k++){
      float av = a[k];
      s0 = fmaf(av, w[k],     s0);
      s1 = fmaf(av, w[K+k],   s1);
      s2 = fmaf(av, w[2*K+k], s2);
      s3 = fmaf(av, w[3*K+k], s3);
    }
    if (RELU){ s0=fmaxf(s0,0.f); s1=fmaxf(s1,0.f); s2=fmaxf(s2,0.f); s3=fmaxf(s3,0.f); }
    if constexpr (OUTBF){
      uint2 uu;
      uu.x = ((unsigned int)f2bf(s1)<<16) | f2bf(s0);
      uu.y = ((unsigned int)f2bf(s3)<<16) | f2bf(s2);
      *(uint2*)((unsigned short*)Op + (size_t)n*64 + c) = uu;
    } else {
      float4 r; r.x=s0; r.y=s1; r.z=s2; r.w=s3;
      *(float4*)((float*)Op + (size_t)n*64 + c) = r;
    }
  }
}

// ---------- fused GATv2 attention+aggregate (pull-based, online softmax) ----------
// wave per segment (dst). Edges pre-sorted by dst (node level) or naturally sorted (batch).
template<int HASEMB, int IDSRC>
__global__ __launch_bounds__(256) void k_gat_fused(
  const int* __restrict__ srcp, const int* __restrict__ segoff,
  const float* __restrict__ xl, const float* __restrict__ xr,
  const unsigned short* __restrict__ emb, const float* __restrict__ att,
  float* __restrict__ agg, int nseg)
{
  int lane = threadIdx.x & 63;
  float av = att[lane];
  int wid = (blockIdx.x*256 + threadIdx.x) >> 6;
  int nw  = (gridDim.x*256) >> 6;
  for (int d = wid; d < nseg; d += nw){
    int e0 = segoff[d], e1 = segoff[d+1];
    float xrv = xr[(size_t)d*64 + lane];
    float m = -3.0e38f, s = 0.f, acc = 0.f;
    for (int e = e0; e < e1; e++){
      int sN = IDSRC ? e : srcp[e];
      float xs = xl[(size_t)sN*64 + lane];
      float v = xs + xrv;
      if (HASEMB) v += bf1(emb[(size_t)e*64 + lane]);
      v = v > 0.f ? v : 0.01f*v;
      float p = v * av;
      #pragma unroll
      for (int o=32;o;o>>=1) p += __shfl_xor(p, o, 64);
      float mn = fmaxf(m, p);
      float cm = expf(m - mn);
      float cp = expf(p - mn);
      s   = s*cm + cp;
      acc = fmaf(acc, cm, cp*xs);
      m = mn;
    }
    agg[(size_t)d*64 + lane] = acc / (s + 1e-16f);
  }
}

// ---------- GRU (h = elu(agg + gat_bias); writes relu(gru) in-place into x) ----------
__global__ __launch_bounds__(256) void k_gru(const float* __restrict__ agg,
  const float* __restrict__ gatb, float* x,
  const float* __restrict__ Wih, const float* __restrict__ Whh,
  const float* __restrict__ bih, const float* __restrict__ bhh, int N)
{
  int n = blockIdx.x*256 + threadIdx.x;
  if (n >= N) return;
  float h[64], xv[64];
  const float4* pa = (const float4*)(agg + (size_t)n*64);
  const float4* px = (const float4*)(x   + (size_t)n*64);
  #pragma unroll
  for (int i=0;i<16;i++){
    float4 avv = pa[i]; float4 xx = px[i];
    h[4*i+0]=eluf(avv.x + gatb[4*i+0]);
    h[4*i+1]=eluf(avv.y + gatb[4*i+1]);
    h[4*i+2]=eluf(avv.z + gatb[4*i+2]);
    h[4*i+3]=eluf(avv.w + gatb[4*i+3]);
    xv[4*i+0]=xx.x; xv[4*i+1]=xx.y; xv[4*i+2]=xx.z; xv[4*i+3]=xx.w;
  }
  for (int c=0;c<64;c++){
    float ir=bih[c], iz=bih[64+c], in2=bih[128+c];
    float hr=bhh[c], hz=bhh[64+c], hn=bhh[128+c];
    const float* wi = Wih + (size_t)c*64;
    const float* wh = Whh + (size_t)c*64;
    #pragma unroll
    for (int k=0;k<64;k++){
      float hk = h[k], xk = xv[k];
      ir  = fmaf(hk, wi[k],      ir);
      iz  = fmaf(hk, wi[4096+k], iz);
      in2 = fmaf(hk, wi[8192+k], in2);
      hr  = fmaf(xk, wh[k],      hr);
      hz  = fmaf(xk, wh[4096+k], hz);
      hn  = fmaf(xk, wh[8192+k], hn);
    }
    float r = 1.f/(1.f + expf(-(ir+hr)));
    float z = 1.f/(1.f + expf(-(iz+hz)));
    float nn = tanhf(in2 + r*hn);
    float o = (1.f - z)*nn + z*xv[c];
    x[(size_t)n*64 + c] = fmaxf(o, 0.f);
  }
}

// ---------- DiffGroupNorm ----------
__global__ __launch_bounds__(256) void k_dgn_s(const float* __restrict__ x,
  const float* __restrict__ WT /*10x64*/, const float* __restrict__ b,
  float* __restrict__ s, int N)
{
  int n = blockIdx.x*256 + threadIdx.x;
  if (n >= N) return;
  float a[64];
  const float4* p = (const float4*)(x + (size_t)n*64);
  #pragma unroll
  for (int i=0;i<16;i++){ float4 v=p[i]; a[4*i]=v.x; a[4*i+1]=v.y; a[4*i+2]=v.z; a[4*i+3]=v.w; }
  float lg[10];
  #pragma unroll
  for (int g=0; g<10; g++){
    float acc = b[g];
    const float* w = WT + (size_t)g*64;
    #pragma unroll
    for (int k=0;k<64;k++) acc = fmaf(a[k], w[k], acc);
    lg[g] = acc;
  }
  float m = lg[0];
  #pragma unroll
  for (int g=1;g<10;g++) m = fmaxf(m, lg[g]);
  float e[10], sum = 0.f;
  #pragma unroll
  for (int g=0;g<10;g++){ e[g] = expf(lg[g]-m); sum += e[g]; }
  float inv = 1.f/sum;
  #pragma unroll
  for (int g=0;g<10;g++) s[(size_t)n*10+g] = e[g]*inv;
}

__global__ __launch_bounds__(640) void k_dgn_stats(const float* __restrict__ s,
  const float* __restrict__ x, float* cs, float* cs2, int N)
{
  int g = threadIdx.x >> 6, f = threadIdx.x & 63;
  int per = (N + gridDim.x - 1) / gridDim.x;
  int n0 = blockIdx.x * per;
  int n1 = min(N, n0 + per);
  float a = 0.f, a2 = 0.f;
  for (int n = n0; n < n1; n++){
    float y = s[(size_t)n*10+g] * x[(size_t)n*64+f];
    a += y; a2 += y*y;
  }
  atomicAdd(&cs [g*64+f], a);
  atomicAdd(&cs2[g*64+f], a2);
}

__global__ void k_dgn_final(const float* cs, const float* cs2,
  const float* __restrict__ bw, const float* __restrict__ bb,
  float* scale, float* shiftsum, int N)
{
  __shared__ float sh[640];
  int i = threadIdx.x;
  float invN = 1.f / (float)N;
  float mean = cs[i]*invN;
  float var  = cs2[i]*invN - mean*mean;
  float sc = bw[i] / sqrtf(var + 1e-5f);
  scale[i] = sc;
  sh[i] = bb[i] - mean*sc;
  __syncthreads();
  if (i < 64){
    float t = 0.f;
    #pragma unroll
    for (int g=0;g<10;g++) t += sh[g*64+i];
    shiftsum[i] = t;
  }
}

__global__ __launch_bounds__(256) void k_dgn_apply(float* x,
  const float* __restrict__ s, const float* __restrict__ scale,
  const float* __restrict__ shiftsum, int N)
{
  int idx = blockIdx.x*256 + threadIdx.x;
  if (idx >= N*64) return;
  int n = idx >> 6, f = idx & 63;
  float ss = 0.f;
  #pragma unroll
  for (int g=0; g<10; g++) ss = fmaf(s[(size_t)n*10+g], scale[g*64+f], ss);
  float xvv = x[idx];
  x[idx] = xvv + 0.01f*(xvv*ss + shiftsum[f]);
}

// ---------- readout ----------
__global__ __launch_bounds__(256) void k_segsum(const float* __restrict__ x,
  const int* __restrict__ batch, float* __restrict__ gout)
{
  int idx = blockIdx.x*256 + threadIdx.x;
  if (idx >= N_NODES*64) return;
  int n = idx >> 6, c = idx & 63;
  atomicAdd(gout + (size_t)batch[n]*64 + c, x[idx]);
}

__global__ __launch_bounds__(256) void k_relu(float* p, int n){
  int i = blockIdx.x*256 + threadIdx.x;
  if (i < n) p[i] = fmaxf(p[i], 0.f);
}

__global__ __launch_bounds__(256) void k_head(const float* __restrict__ y,
  const float* __restrict__ w, const float* __restrict__ b,
  float* __restrict__ out, int N)
{
  int n = blockIdx.x*256 + threadIdx.x;
  if (n >= N) return;
  float acc = b[0];
  const float4* p = (const float4*)(y + (size_t)n*64);
  #pragma unroll
  for (int i=0;i<16;i++){
    float4 v = p[i];
    acc = fmaf(v.x, w[4*i+0], acc);
    acc = fmaf(v.y, w[4*i+1], acc);
    acc = fmaf(v.z, w[4*i+2], acc);
    acc = fmaf(v.w, w[4*i+3], acc);
  }
  out[n] = acc;
}

// ---------- host ----------
extern "C" void kernel_launch(void* const* d_in, const int* in_sizes, int n_in,
                              void* d_out, int out_size, void* d_ws, size_t ws_size,
                              hipStream_t stream) {
  (void)in_sizes; (void)n_in; (void)out_size; (void)ws_size;

  // ----- workspace layout -----
  char* base = (char*)d_ws; size_t off = 0;
  auto A = [&](size_t bytes)->void*{ void* p = base + off; off += (bytes + 255) & ~(size_t)255; return p; };
  unsigned short* e_emb = (unsigned short*)A((size_t)N_EDGES*64*2);   // bf16 e_emb (sorted order)
  float* xbuf   = (float*)A((size_t)N_NODES*64*4);
  float* xl     = (float*)A((size_t)N_NODES*64*4);
  float* xr     = (float*)A((size_t)N_NODES*64*4);
  float* agg    = (float*)A((size_t)N_NODES*64*4);
  int*   perm   = (int*)A((size_t)N_EDGES*4);
  int*   srcp   = (int*)A((size_t)N_EDGES*4);
  int*   segoff = (int*)A((size_t)(N_NODES+1)*4);
  int*   cursor = (int*)A((size_t)N_NODES*4);
  int*   bsum   = (int*)A(512*4);
  int*   bo     = (int*)A(512*4);
  int*   goff   = (int*)A((size_t)(N_GRAPHS+1)*4);
  float* sbuf   = (float*)A((size_t)N_NODES*10*4);
  float* gout   = (float*)A((size_t)N_GRAPHS*64*4);
  float* ybuf   = (float*)A((size_t)N_GRAPHS*64*4);
  float* ybuf2  = (float*)A((size_t)N_GRAPHS*64*4);
  float* colsum = (float*)A(2*640*4); float* colsumsq = colsum + 640;
  float* scale  = (float*)A((640+64)*4); float* shiftsum = scale + 640;
  unsigned short* W1Tb  = (unsigned short*)A(4096*2);
  unsigned short* W2Tb0 = (unsigned short*)A(4096*2);
  unsigned short* W2Tb1 = (unsigned short*)A(4096*2);
  float* wf     = (float*)A(60000*4);
  size_t wo = 0;
  auto W = [&](size_t n)->float*{ float* p = wf + wo; wo += n; return p; };

  float* pre_nWT = W(64*92);
  float* WlT[2] = {W(4096), W(4096)};
  float* WrT[2] = {W(4096), W(4096)};
  float* gnWT[2] = {W(640), W(640)};
  float* gWlT = W(4096);
  float* gWrT = W(4096);
  float* ggnWT = W(640);
  float* postWT[2] = {W(4096), W(4096)};

  const float* F[48];
  for (int i=0;i<41;i++) F[i] = (const float*)d_in[i];

  // ----- transpose table -----
  CvtArgs ca; ca.cnt = 0;
  auto addT = [&](const float* s, float* d, int r, int c){
    ca.e[ca.cnt].s=s; ca.e[ca.cnt].d=d; ca.e[ca.cnt].rows=r; ca.e[ca.cnt].cols=c; ca.cnt++; };

  addT(F[4],  pre_nWT, 92, 64);
  for (int l=0;l<2;l++) addT(F[8]  + l*4096, WlT[l], 64, 64);
  for (int l=0;l<2;l++) addT(F[10] + l*4096, WrT[l], 64, 64);
  for (int l=0;l<2;l++) addT(F[19] + l*640,  gnWT[l], 64, 10);
  addT(F[23], gWlT, 64, 64);
  addT(F[25], gWrT, 64, 64);
  addT(F[33], ggnWT, 64, 10);
  for (int l=0;l<2;l++) addT(F[37] + l*4096, postWT[l], 64, 64);

  const int* src   = (const int*)d_in[1];
  const int* dst   = src + N_EDGES;
  const int* batch = (const int*)d_in[3];

  const int NBn = (N_NODES + 255)/256;    // 391
  const int NBg = (N_GRAPHS + 255)/256;   // 4
  const int NBa = (N_NODES*64)/256;       // 25000
  const int NBemb = N_EDGES/64;           // 25000

  k_convert<<<dim3(24, ca.cnt), 256, 0, stream>>>(ca);
  k_wprep<<<16,256,0,stream>>>(F[6], F[12], F[12]+4096, W1Tb, W2Tb0, W2Tb1);

  // ----- CSR build (dst-sorted edge list), once per launch -----
  hipMemsetAsync(cursor, 0, (size_t)N_NODES*4, stream);
  k_hist<<<2048,256,0,stream>>>(dst, cursor);
  k_scan1<<<NBn,256,0,stream>>>(cursor, segoff, bsum, N_NODES);
  k_scan2<<<1,512,0,stream>>>(bsum, bo, NBn);
  k_scan3<<<NBn,256,0,stream>>>(segoff, bo, cursor, N_NODES);
  k_scatter<<<2048,256,0,stream>>>(src, dst, cursor, srcp, perm);
  k_goff<<<NBn,256,0,stream>>>(batch, goff);

  // x = relu(x_in @ pre_nW + pre_nb)
  k_linear64<92,1,0,0,1><<<NBn,256,0,stream>>>(F[0], pre_nWT, F[5], xbuf, N_NODES);

  for (int l=0; l<2; l++){
    // e_emb = relu(edge_attr @ pre_eW + pre_eb) @ We[l]   (fused MFMA, bf16, sorted order)
    k_edge_emb<<<NBemb,256,0,stream>>>(F[2], perm, W1Tb, F[7], (l==0)?W2Tb0:W2Tb1, e_emb, N_EDGES);

    for (int t=0; t<2; t++){
      k_linear64<64,0,0,0,1><<<NBn,256,0,stream>>>(xbuf, WlT[l], F[9]  + l*64, xl, N_NODES);
      k_linear64<64,0,0,0,1><<<NBn,256,0,stream>>>(xbuf, WrT[l], F[11] + l*64, xr, N_NODES);
      k_gat_fused<1,0><<<4096,256,0,stream>>>(srcp, segoff, xl, xr, e_emb,
                                              F[13] + l*64, agg, N_NODES);
      k_gru<<<NBn,256,0,stream>>>(agg, F[14] + l*64, xbuf, F[15] + l*12288, F[16] + l*12288,
                                  F[17] + l*192, F[18] + l*192, N_NODES);
    }
    hipMemsetAsync(colsum, 0, 2*640*4, stream);
    k_dgn_s<<<NBn,256,0,stream>>>(xbuf, gnWT[l], F[20] + l*10, sbuf, N_NODES);
    k_dgn_stats<<<128,640,0,stream>>>(sbuf, xbuf, colsum, colsumsq, N_NODES);
    k_dgn_final<<<1,640,0,stream>>>(colsum, colsumsq, F[21] + l*640, F[22] + l*640, scale, shiftsum, N_NODES);
    k_dgn_apply<<<NBa,256,0,stream>>>(xbuf, sbuf, scale, shiftsum, N_NODES);
  }

  // readout: out = relu(segment_sum(x, batch))
  hipMemsetAsync(gout, 0, (size_t)N_GRAPHS*64*4, stream);
  k_segsum<<<NBa,256,0,stream>>>(xbuf, batch, gout);
  k_relu<<<(N_GRAPHS*64+255)/256,256,0,stream>>>(gout, N_GRAPHS*64);

  // xl_g fixed across both timesteps (x doesn't change here)
  k_linear64<64,0,0,0,1><<<NBn,256,0,stream>>>(xbuf, gWlT, F[24], xl, N_NODES);
  for (int t=0; t<2; t++){
    k_linear64<64,0,0,0,1><<<NBg,256,0,stream>>>(gout, gWrT, F[26], xr, N_GRAPHS);
    k_gat_fused<0,1><<<256,256,0,stream>>>(nullptr, goff, xl, xr, nullptr,
                                           F[27], agg, N_GRAPHS);
    k_gru<<<NBg,256,0,stream>>>(agg, F[28], gout, F[29], F[30], F[31], F[32], N_GRAPHS);
  }

  hipMemsetAsync(colsum, 0, 2*640*4, stream);
  k_dgn_s<<<NBg,256,0,stream>>>(gout, ggnWT, F[34], sbuf, N_GRAPHS);
  k_dgn_stats<<<8,640,0,stream>>>(sbuf, gout, colsum, colsumsq, N_GRAPHS);
  k_dgn_final<<<1,640,0,stream>>>(colsum, colsumsq, F[35], F[36], scale, shiftsum, N_GRAPHS);
  k_dgn_apply<<<(N_GRAPHS*64+255)/256,256,0,stream>>>(gout, sbuf, scale, shiftsum, N_GRAPHS);

  // post MLP + head
  k_linear64<64,1,0,0,1><<<NBg,256,0,stream>>>(gout, postWT[0], F[38],      ybuf,  N_GRAPHS);
  k_linear64<64,1,0,0,1><<<NBg,256,0,stream>>>(ybuf, postWT[1], F[38] + 64, ybuf2, N_GRAPHS);
  k_head<<<NBg,256,0,stream>>>(ybuf2, F[39], F[40], (float*)d_out, N_GRAPHS);
}

// Round 4
// 3825.232 us; speedup vs baseline: 2.3088x; 1.5035x over previous
//
#include <hip/hip_runtime.h>
#include <hip/hip_bf16.h>

#define N_NODES 100000
#define N_EDGES 1600000
#define N_GRAPHS 1000
#define HID 64
#define GRP 10

typedef __attribute__((ext_vector_type(8))) short bf16x8;
typedef __attribute__((ext_vector_type(4))) float f32x4;

// ---------- helpers ----------
__device__ __forceinline__ float bf1(unsigned short u){ union{unsigned int x; float f;} v; v.x = ((unsigned int)u)<<16; return v.f; }
__device__ __forceinline__ float bf_lo(unsigned int u){ union{unsigned int x; float f;} v; v.x = u<<16; return v.f; }
__device__ __forceinline__ float bf_hi(unsigned int u){ union{unsigned int x; float f;} v; v.x = u & 0xFFFF0000u; return v.f; }
__device__ __forceinline__ unsigned short f2bf(float f){
  union{float f; unsigned int i;} v; v.f = f;
  unsigned int r = v.i + 0x7FFFu + ((v.i >> 16) & 1u);
  return (unsigned short)(r >> 16);
}
__device__ __forceinline__ float eluf(float v){ return v > 0.f ? v : expm1f(v); }
__device__ __forceinline__ float sigf(float v){ return 1.f/(1.f + expf(-v)); }

// ---------- weight transpose (f32 -> f32) ----------
struct CvtEnt { const float* s; float* d; int rows; int cols; };
struct CvtArgs { CvtEnt e[16]; int cnt; };

__global__ __launch_bounds__(256) void k_convert(CvtArgs a){
  CvtEnt E = a.e[blockIdx.y];
  int n = E.rows * E.cols;
  for (int i = blockIdx.x*256 + threadIdx.x; i < n; i += gridDim.x*256){
    int r = i / E.cols, c = i % E.cols;
    E.d[(size_t)c*E.rows + r] = E.s[i];
  }
}

// ---------- split-bf16 weight prep: dst[n][k] (BT rows), hi/lo pair ----------
struct SpEnt { const float* s; unsigned short* dhi; unsigned short* dlo; int n; int k; int trans; };
struct SpArgs { SpEnt e[12]; int cnt; };

__global__ __launch_bounds__(256) void k_wsplit(SpArgs a){
  SpEnt E = a.e[blockIdx.y];
  int tot = E.n * E.k;
  for (int i = blockIdx.x*256 + threadIdx.x; i < tot; i += gridDim.x*256){
    int nr = i / E.k, kc = i - nr*E.k;
    float v = E.trans ? E.s[(size_t)kc*E.n + nr] : E.s[i];
    unsigned short hi = f2bf(v);
    unsigned short lo = f2bf(v - bf1(hi));
    E.dhi[i] = hi; E.dlo[i] = lo;
  }
}

// bf16 transposed (and K-padded) weights for the MFMA edge-embedding kernel.
__global__ __launch_bounds__(256) void k_wprep(const float* __restrict__ W1,
  const float* __restrict__ W2a, const float* __restrict__ W2b,
  unsigned short* __restrict__ W1Tb, unsigned short* __restrict__ W2Tba,
  unsigned short* __restrict__ W2Tbb)
{
  int i = blockIdx.x*256 + threadIdx.x;   // 0..4095
  if (i >= 4096) return;
  int out = i & 63, k = i >> 6;
  int ks = k < 50 ? k : 0;
  unsigned short v1 = f2bf(W1[ks*64 + out]);
  if (k >= 50) v1 = 0;
  W1Tb [out*64 + k] = v1;
  W2Tba[out*64 + k] = f2bf(W2a[k*64 + out]);
  W2Tbb[out*64 + k] = f2bf(W2b[k*64 + out]);
}

// ---------- CSR build: histogram -> scan -> scatter ----------
__global__ __launch_bounds__(256) void k_hist(const int* __restrict__ dst, int* __restrict__ cnt){
  for (int e = blockIdx.x*256 + threadIdx.x; e < N_EDGES; e += gridDim.x*256)
    atomicAdd(cnt + dst[e], 1);
}

__global__ __launch_bounds__(256) void k_scan1(const int* __restrict__ cnt,
  int* __restrict__ excl, int* __restrict__ bsum, int N)
{
  __shared__ int sh[256];
  int t = threadIdx.x;
  int i = blockIdx.x*256 + t;
  int v = (i < N) ? cnt[i] : 0;
  sh[t] = v;
  __syncthreads();
  #pragma unroll
  for (int o=1;o<256;o<<=1){
    int x = (t>=o) ? sh[t-o] : 0;
    __syncthreads();
    sh[t] += x;
    __syncthreads();
  }
  if (i < N) excl[i] = sh[t] - v;
  if (t == 255) bsum[blockIdx.x] = sh[255];
}

__global__ __launch_bounds__(512) void k_scan2(const int* __restrict__ bsum,
  int* __restrict__ bo, int NB)
{
  __shared__ int sh[512];
  int t = threadIdx.x;
  int v = (t < NB) ? bsum[t] : 0;
  sh[t] = v;
  __syncthreads();
  #pragma unroll
  for (int o=1;o<512;o<<=1){
    int x = (t>=o) ? sh[t-o] : 0;
    __syncthreads();
    sh[t] += x;
    __syncthreads();
  }
  if (t < NB) bo[t] = sh[t] - v;
}

__global__ __launch_bounds__(256) void k_scan3(int* __restrict__ segoff,
  const int* __restrict__ bo, int* __restrict__ cursor, int N)
{
  int i = blockIdx.x*256 + threadIdx.x;
  if (i >= N) return;
  int v = segoff[i] + bo[i>>8];
  segoff[i] = v;
  cursor[i] = v;
  if (i == 0) segoff[N] = N_EDGES;
}

__global__ __launch_bounds__(256) void k_scatter(const int* __restrict__ src,
  const int* __restrict__ dst, int* __restrict__ cursor,
  int* __restrict__ srcp, int* __restrict__ perm)
{
  for (int e = blockIdx.x*256 + threadIdx.x; e < N_EDGES; e += gridDim.x*256){
    int d = dst[e];
    int pos = atomicAdd(cursor + d, 1);
    srcp[pos] = src[e];
    perm[pos] = e;
  }
}

// graph segment offsets from sorted batch array
__global__ __launch_bounds__(256) void k_goff(const int* __restrict__ batch, int* __restrict__ goff){
  for (int n = blockIdx.x*256 + threadIdx.x; n < N_NODES; n += gridDim.x*256){
    int b = batch[n];
    int prev = (n==0) ? -1 : batch[n-1];
    for (int g = prev+1; g <= b; g++) goff[g] = n;
    if (n == N_NODES-1){ for (int g=b+1; g<=N_GRAPHS; g++) goff[g] = N_NODES; }
  }
}

// ---------- fused MFMA edge embedding (gathers rows via perm, writes sorted order) ----------
__global__ __launch_bounds__(256) void k_edge_emb(
  const float* __restrict__ EA, const int* __restrict__ perm,
  const unsigned short* __restrict__ W1Tb,
  const float* __restrict__ b1, const unsigned short* __restrict__ W2Tb,
  unsigned short* __restrict__ out, int nE)
{
  __shared__ float ea[64*50];              // fp32 input tile (reused as out staging)
  __shared__ unsigned short hb[64*72];     // bf16 hidden tile, pitch 72
  __shared__ int prm[64];

  int tid = threadIdx.x;
  int lane = tid & 63;
  int wave = tid >> 6;
  int row16 = lane & 15;
  int kg = lane >> 4;                      // k-group 0..3
  long tile = (long)blockIdx.x * 64;

  // weight fragments (L2-resident)
  bf16x8 w1[4][2], w2[4][2];
  #pragma unroll
  for (int n=0;n<4;n++){
    #pragma unroll
    for (int kk=0;kk<2;kk++){
      w1[n][kk] = *(const bf16x8*)(W1Tb + (n*16+row16)*64 + kk*32 + kg*8);
      w2[n][kk] = *(const bf16x8*)(W2Tb + (n*16+row16)*64 + kk*32 + kg*8);
    }
  }
  float bias[4];
  #pragma unroll
  for (int n=0;n<4;n++) bias[n] = b1[n*16+row16];

  if (tid < 64) prm[tid] = perm[tile + tid];
  __syncthreads();

  // stage edge_attr tile (64 permuted rows x 50 f32) as float2
  for (int j = tid; j < 1600; j += 256){
    int row = j/25, c2 = j - row*25;
    *(float2*)(ea + row*50 + c2*2) = *(const float2*)(EA + (size_t)prm[row]*50 + c2*2);
  }
  __syncthreads();

  // stage1 A-frags (fp32 -> bf16 in-register)
  int r = wave*16 + row16;
  bf16x8 a0, a1;
  {
    const float* p = ea + r*50;
    #pragma unroll
    for (int i=0;i<8;i++) ((short*)&a0)[i] = (short)f2bf(p[kg*8+i]);
    #pragma unroll
    for (int i=0;i<8;i++){
      int k = 32 + kg*8 + i;
      ((short*)&a1)[i] = (short)((k < 50) ? f2bf(p[k]) : (unsigned short)0);
    }
  }
  f32x4 c[4];
  #pragma unroll
  for (int n=0;n<4;n++){
    f32x4 acc = {0.f,0.f,0.f,0.f};
    acc = __builtin_amdgcn_mfma_f32_16x16x32_bf16(a0, w1[n][0], acc, 0,0,0);
    acc = __builtin_amdgcn_mfma_f32_16x16x32_bf16(a1, w1[n][1], acc, 0,0,0);
    c[n] = acc;
  }
  // bias + relu, h -> LDS (bf16)
  #pragma unroll
  for (int n=0;n<4;n++){
    #pragma unroll
    for (int q=0;q<4;q++){
      float v = fmaxf(c[n][q] + bias[n], 0.f);
      hb[(wave*16 + kg*4 + q)*72 + n*16 + row16] = f2bf(v);
    }
  }
  __syncthreads();

  // stage2 A-frags from LDS
  bf16x8 ha, hc;
  {
    const unsigned short* p = hb + r*72;
    ha = *(const bf16x8*)(p + kg*8);
    hc = *(const bf16x8*)(p + 32 + kg*8);
  }
  f32x4 d[4];
  #pragma unroll
  for (int n=0;n<4;n++){
    f32x4 acc = {0.f,0.f,0.f,0.f};
    acc = __builtin_amdgcn_mfma_f32_16x16x32_bf16(ha, w2[n][0], acc, 0,0,0);
    acc = __builtin_amdgcn_mfma_f32_16x16x32_bf16(hc, w2[n][1], acc, 0,0,0);
    d[n] = acc;
  }
  __syncthreads();
  // stage out tile in LDS (reuse ea region)
  unsigned short* ob = (unsigned short*)ea;
  #pragma unroll
  for (int n=0;n<4;n++){
    #pragma unroll
    for (int q=0;q<4;q++)
      ob[(wave*16 + kg*4 + q)*72 + n*16 + row16] = f2bf(d[n][q]);
  }
  __syncthreads();

  // coalesced store: 64 rows x 128B, thread t handles 32B
  {
    int rr = tid >> 2, q = tid & 3;
    const uint4* s = (const uint4*)(ob + rr*72 + q*16);
    uint4 v0 = s[0], v1 = s[1];
    uint4* gp = (uint4*)(out + (tile + rr)*64 + q*16);
    gp[0] = v0; gp[1] = v1;
  }
}

// ---------- split-bf16 staging helper macro body: write hi/lo 4-short packs ----------
__device__ __forceinline__ void pack4(unsigned short* hi, unsigned short* lo, int ofs,
                                      float v0, float v1, float v2, float v3){
  unsigned short h0=f2bf(v0), h1=f2bf(v1), h2=f2bf(v2), h3=f2bf(v3);
  unsigned short l0=f2bf(v0-bf1(h0)), l1=f2bf(v1-bf1(h1)), l2=f2bf(v2-bf1(h2)), l3=f2bf(v3-bf1(h3));
  uint2 ph, pl;
  ph.x = ((unsigned int)h1<<16)|h0; ph.y = ((unsigned int)h3<<16)|h2;
  pl.x = ((unsigned int)l1<<16)|l0; pl.y = ((unsigned int)l3<<16)|l2;
  *(uint2*)(hi + ofs) = ph;
  *(uint2*)(lo + ofs) = pl;
}

// ---------- MFMA linear (split-bf16, ~fp32 accurate): out = X@W + b, optional dual output ----------
// W*hi/W*lo are BT rows [64 out][64 k] bf16.
template<int DUAL, int RELU>
__global__ __launch_bounds__(256) void k_lin_mfma(
  const float* __restrict__ X,
  const unsigned short* __restrict__ WAhi, const unsigned short* __restrict__ WAlo,
  const float* __restrict__ bA, float* __restrict__ outA,
  const unsigned short* __restrict__ WBhi, const unsigned short* __restrict__ WBlo,
  const float* __restrict__ bB, float* __restrict__ outB, int N)
{
  __shared__ unsigned short xh[64*72], xlo[64*72];
  int tid = threadIdx.x, lane = tid & 63, wave = tid >> 6;
  int col = lane & 15, kg = lane >> 4;
  long base = (long)blockIdx.x * 64;

  for (int idx = tid; idx < 1024; idx += 256){
    int r = idx >> 4, q = idx & 15;
    long row = base + r;
    float4 v = {0,0,0,0};
    if (row < N) v = ((const float4*)X)[row*16 + q];
    pack4(xh, xlo, r*72 + q*4, v.x, v.y, v.z, v.w);
  }
  __syncthreads();

  int r = wave*16 + col;
  bf16x8 ah[2], al[2];
  ah[0] = *(const bf16x8*)(xh  + r*72 + kg*8);
  ah[1] = *(const bf16x8*)(xh  + r*72 + 32 + kg*8);
  al[0] = *(const bf16x8*)(xlo + r*72 + kg*8);
  al[1] = *(const bf16x8*)(xlo + r*72 + 32 + kg*8);

  #pragma unroll
  for (int ct = 0; ct < 4; ct++){
    f32x4 aA = {0,0,0,0}, aB = {0,0,0,0};
    #pragma unroll
    for (int kk = 0; kk < 2; kk++){
      int wofs = (ct*16 + col)*64 + kk*32 + kg*8;
      bf16x8 bh = *(const bf16x8*)(WAhi + wofs);
      bf16x8 bl = *(const bf16x8*)(WAlo + wofs);
      aA = __builtin_amdgcn_mfma_f32_16x16x32_bf16(ah[kk], bh, aA, 0,0,0);
      aA = __builtin_amdgcn_mfma_f32_16x16x32_bf16(al[kk], bh, aA, 0,0,0);
      aA = __builtin_amdgcn_mfma_f32_16x16x32_bf16(ah[kk], bl, aA, 0,0,0);
      if (DUAL){
        bf16x8 ch = *(const bf16x8*)(WBhi + wofs);
        bf16x8 cl = *(const bf16x8*)(WBlo + wofs);
        aB = __builtin_amdgcn_mfma_f32_16x16x32_bf16(ah[kk], ch, aB, 0,0,0);
        aB = __builtin_amdgcn_mfma_f32_16x16x32_bf16(al[kk], ch, aB, 0,0,0);
        aB = __builtin_amdgcn_mfma_f32_16x16x32_bf16(ah[kk], cl, aB, 0,0,0);
      }
    }
    int c = ct*16 + col;
    float bAv = bA[c];
    float bBv = DUAL ? bB[c] : 0.f;
    #pragma unroll
    for (int reg = 0; reg < 4; reg++){
      long gr = base + wave*16 + kg*4 + reg;
      if (gr < N){
        float vA = aA[reg] + bAv;
        if (RELU) vA = fmaxf(vA, 0.f);
        outA[gr*64 + c] = vA;
        if (DUAL){
          float vB = aB[reg] + bBv;
          if (RELU) vB = fmaxf(vB, 0.f);
          outB[gr*64 + c] = vB;
        }
      }
    }
  }
}

// ---------- MFMA GRU: h = elu(agg+gatb); x = relu(gru(h, x)) in-place ----------
// Wih/Whh given [192][64] row-major == BT rows directly; hi/lo split-bf16.
__global__ __launch_bounds__(256) void k_gru_mfma(
  const float* __restrict__ agg, const float* __restrict__ gatb,
  float* __restrict__ x,
  const unsigned short* __restrict__ Wih_hi, const unsigned short* __restrict__ Wih_lo,
  const unsigned short* __restrict__ Whh_hi, const unsigned short* __restrict__ Whh_lo,
  const float* __restrict__ bih, const float* __restrict__ bhh, int N)
{
  __shared__ unsigned short hh_[64*72], hl_[64*72], xh_[64*72], xl_[64*72];
  int tid = threadIdx.x, lane = tid & 63, wave = tid >> 6;
  int col = lane & 15, kg = lane >> 4;
  long base = (long)blockIdx.x * 64;

  for (int idx = tid; idx < 1024; idx += 256){
    int r = idx >> 4, q = idx & 15;
    long row = base + r;
    float4 a = {0,0,0,0}, xx = {0,0,0,0};
    if (row < N){
      a  = ((const float4*)agg)[row*16 + q];
      xx = ((const float4*)x)[row*16 + q];
    }
    float h0 = eluf(a.x + gatb[q*4+0]);
    float h1 = eluf(a.y + gatb[q*4+1]);
    float h2 = eluf(a.z + gatb[q*4+2]);
    float h3 = eluf(a.w + gatb[q*4+3]);
    pack4(hh_, hl_, r*72 + q*4, h0, h1, h2, h3);
    pack4(xh_, xl_, r*72 + q*4, xx.x, xx.y, xx.z, xx.w);
  }
  __syncthreads();

  int r = wave*16 + col;
  bf16x8 hhi[2], hlo[2], xhi[2], xlo2[2];
  hhi[0] = *(const bf16x8*)(hh_ + r*72 + kg*8);
  hhi[1] = *(const bf16x8*)(hh_ + r*72 + 32 + kg*8);
  hlo[0] = *(const bf16x8*)(hl_ + r*72 + kg*8);
  hlo[1] = *(const bf16x8*)(hl_ + r*72 + 32 + kg*8);
  xhi[0] = *(const bf16x8*)(xh_ + r*72 + kg*8);
  xhi[1] = *(const bf16x8*)(xh_ + r*72 + 32 + kg*8);
  xlo2[0] = *(const bf16x8*)(xl_ + r*72 + kg*8);
  xlo2[1] = *(const bf16x8*)(xl_ + r*72 + 32 + kg*8);

  #pragma unroll
  for (int ct = 0; ct < 4; ct++){
    f32x4 ai[3], ah[3];
    #pragma unroll
    for (int g=0; g<3; g++){ ai[g] = (f32x4){0,0,0,0}; ah[g] = (f32x4){0,0,0,0}; }
    #pragma unroll
    for (int g = 0; g < 3; g++){
      int nt = g*4 + ct;
      #pragma unroll
      for (int kk = 0; kk < 2; kk++){
        int wofs = (nt*16 + col)*64 + kk*32 + kg*8;
        bf16x8 bh = *(const bf16x8*)(Wih_hi + wofs);
        bf16x8 bl = *(const bf16x8*)(Wih_lo + wofs);
        ai[g] = __builtin_amdgcn_mfma_f32_16x16x32_bf16(hhi[kk], bh, ai[g], 0,0,0);
        ai[g] = __builtin_amdgcn_mfma_f32_16x16x32_bf16(hlo[kk], bh, ai[g], 0,0,0);
        ai[g] = __builtin_amdgcn_mfma_f32_16x16x32_bf16(hhi[kk], bl, ai[g], 0,0,0);
        bf16x8 ch = *(const bf16x8*)(Whh_hi + wofs);
        bf16x8 cl = *(const bf16x8*)(Whh_lo + wofs);
        ah[g] = __builtin_amdgcn_mfma_f32_16x16x32_bf16(xhi[kk], ch, ah[g], 0,0,0);
        ah[g] = __builtin_amdgcn_mfma_f32_16x16x32_bf16(xlo2[kk], ch, ah[g], 0,0,0);
        ah[g] = __builtin_amdgcn_mfma_f32_16x16x32_bf16(xhi[kk], cl, ah[g], 0,0,0);
      }
    }
    int c = ct*16 + col;
    float bi0 = bih[c], bi1 = bih[64+c], bi2 = bih[128+c];
    float bh0 = bhh[c], bh1 = bhh[64+c], bh2 = bhh[128+c];
    #pragma unroll
    for (int reg = 0; reg < 4; reg++){
      int rr = wave*16 + kg*4 + reg;
      long gr = base + rr;
      float ir = ai[0][reg] + bi0, iz = ai[1][reg] + bi1, in2 = ai[2][reg] + bi2;
      float hr = ah[0][reg] + bh0, hz = ah[1][reg] + bh1, hn = ah[2][reg] + bh2;
      float xv = bf1(xh_[rr*72 + c]) + bf1(xl_[rr*72 + c]);
      float r_ = sigf(ir + hr);
      float z  = sigf(iz + hz);
      float nn = tanhf(in2 + r_*hn);
      float o = (1.f - z)*nn + z*xv;
      if (gr < N) x[gr*64 + c] = fmaxf(o, 0.f);
    }
  }
}

// ---------- generic linear: out[n,0..63] = act(A[n,:] @ W + b) ----------
template<int K, int RELU, int INBF, int OUTBF, int HASB>
__global__ __launch_bounds__(256) void k_linear64(const void* Ap,
    const float* __restrict__ WT, const float* __restrict__ bias, void* Op, int N)
{
  int n = blockIdx.x*256 + threadIdx.x;
  if (n >= N) return;
  float a[K];
  if constexpr (INBF){
    const unsigned int* p = (const unsigned int*)((const unsigned short*)Ap + (size_t)n*K);
    #pragma unroll
    for (int i=0;i<K/2;i++){ unsigned int u=p[i]; a[2*i]=bf_lo(u); a[2*i+1]=bf_hi(u); }
  } else if constexpr (K % 4 == 0){
    const float4* p = (const float4*)((const float*)Ap + (size_t)n*K);
    #pragma unroll
    for (int i=0;i<K/4;i++){ float4 v=p[i]; a[4*i]=v.x; a[4*i+1]=v.y; a[4*i+2]=v.z; a[4*i+3]=v.w; }
  } else {
    const float2* p = (const float2*)((const float*)Ap + (size_t)n*K);
    #pragma unroll
    for (int i=0;i<K/2;i++){ float2 v=p[i]; a[2*i]=v.x; a[2*i+1]=v.y; }
  }
  for (int c=0;c<64;c+=4){
    float s0 = HASB ? bias[c+0] : 0.f;
    float s1 = HASB ? bias[c+1] : 0.f;
    float s2 = HASB ? bias[c+2] : 0.f;
    float s3 = HASB ? bias[c+3] : 0.f;
    const float* w = WT + (size_t)c*K;
    #pragma unroll
    for (int k=0;k<K;k++){
      float av = a[k];
      s0 = fmaf(av, w[k],     s0);
      s1 = fmaf(av, w[K+k],   s1);
      s2 = fmaf(av, w[2*K+k], s2);
      s3 = fmaf(av, w[3*K+k], s3);
    }
    if (RELU){ s0=fmaxf(s0,0.f); s1=fmaxf(s1,0.f); s2=fmaxf(s2,0.f); s3=fmaxf(s3,0.f); }
    if constexpr (OUTBF){
      uint2 uu;
      uu.x = ((unsigned int)f2bf(s1)<<16) | f2bf(s0);
      uu.y = ((unsigned int)f2bf(s3)<<16) | f2bf(s2);
      *(uint2*)((unsigned short*)Op + (size_t)n*64 + c) = uu;
    } else {
      float4 r; r.x=s0; r.y=s1; r.z=s2; r.w=s3;
      *(float4*)((float*)Op + (size_t)n*64 + c) = r;
    }
  }
}

// ---------- fused GATv2 attention+aggregate (pull-based, online softmax) ----------
template<int HASEMB, int IDSRC>
__global__ __launch_bounds__(256) void k_gat_fused(
  const int* __restrict__ srcp, const int* __restrict__ segoff,
  const float* __restrict__ xl, const float* __restrict__ xr,
  const unsigned short* __restrict__ emb, const float* __restrict__ att,
  float* __restrict__ agg, int nseg)
{
  int lane = threadIdx.x & 63;
  float av = att[lane];
  int wid = (blockIdx.x*256 + threadIdx.x) >> 6;
  int nw  = (gridDim.x*256) >> 6;
  for (int d = wid; d < nseg; d += nw){
    int e0 = segoff[d], e1 = segoff[d+1];
    float xrv = xr[(size_t)d*64 + lane];
    float m = -3.0e38f, s = 0.f, acc = 0.f;
    for (int e = e0; e < e1; e++){
      int sN = IDSRC ? e : srcp[e];
      float xs = xl[(size_t)sN*64 + lane];
      float v = xs + xrv;
      if (HASEMB) v += bf1(emb[(size_t)e*64 + lane]);
      v = v > 0.f ? v : 0.01f*v;
      float p = v * av;
      #pragma unroll
      for (int o=32;o;o>>=1) p += __shfl_xor(p, o, 64);
      float mn = fmaxf(m, p);
      float cm = expf(m - mn);
      float cp = expf(p - mn);
      s   = s*cm + cp;
      acc = fmaf(acc, cm, cp*xs);
      m = mn;
    }
    agg[(size_t)d*64 + lane] = acc / (s + 1e-16f);
  }
}

// ---------- DiffGroupNorm ----------
__global__ __launch_bounds__(256) void k_dgn_s(const float* __restrict__ x,
  const float* __restrict__ WT /*10x64*/, const float* __restrict__ b,
  float* __restrict__ s, int N)
{
  int n = blockIdx.x*256 + threadIdx.x;
  if (n >= N) return;
  float a[64];
  const float4* p = (const float4*)(x + (size_t)n*64);
  #pragma unroll
  for (int i=0;i<16;i++){ float4 v=p[i]; a[4*i]=v.x; a[4*i+1]=v.y; a[4*i+2]=v.z; a[4*i+3]=v.w; }
  float lg[10];
  #pragma unroll
  for (int g=0; g<10; g++){
    float acc = b[g];
    const float* w = WT + (size_t)g*64;
    #pragma unroll
    for (int k=0;k<64;k++) acc = fmaf(a[k], w[k], acc);
    lg[g] = acc;
  }
  float m = lg[0];
  #pragma unroll
  for (int g=1;g<10;g++) m = fmaxf(m, lg[g]);
  float e[10], sum = 0.f;
  #pragma unroll
  for (int g=0;g<10;g++){ e[g] = expf(lg[g]-m); sum += e[g]; }
  float inv = 1.f/sum;
  #pragma unroll
  for (int g=0;g<10;g++) s[(size_t)n*10+g] = e[g]*inv;
}

__global__ __launch_bounds__(640) void k_dgn_stats(const float* __restrict__ s,
  const float* __restrict__ x, float* cs, float* cs2, int N)
{
  int g = threadIdx.x >> 6, f = threadIdx.x & 63;
  int per = (N + gridDim.x - 1) / gridDim.x;
  int n0 = blockIdx.x * per;
  int n1 = min(N, n0 + per);
  float a = 0.f, a2 = 0.f;
  for (int n = n0; n < n1; n++){
    float y = s[(size_t)n*10+g] * x[(size_t)n*64+f];
    a += y; a2 += y*y;
  }
  atomicAdd(&cs [g*64+f], a);
  atomicAdd(&cs2[g*64+f], a2);
}

__global__ void k_dgn_final(const float* cs, const float* cs2,
  const float* __restrict__ bw, const float* __restrict__ bb,
  float* scale, float* shiftsum, int N)
{
  __shared__ float sh[640];
  int i = threadIdx.x;
  float invN = 1.f / (float)N;
  float mean = cs[i]*invN;
  float var  = cs2[i]*invN - mean*mean;
  float sc = bw[i] / sqrtf(var + 1e-5f);
  scale[i] = sc;
  sh[i] = bb[i] - mean*sc;
  __syncthreads();
  if (i < 64){
    float t = 0.f;
    #pragma unroll
    for (int g=0;g<10;g++) t += sh[g*64+i];
    shiftsum[i] = t;
  }
}

__global__ __launch_bounds__(256) void k_dgn_apply(float* x,
  const float* __restrict__ s, const float* __restrict__ scale,
  const float* __restrict__ shiftsum, int N)
{
  int idx = blockIdx.x*256 + threadIdx.x;
  if (idx >= N*64) return;
  int n = idx >> 6, f = idx & 63;
  float ss = 0.f;
  #pragma unroll
  for (int g=0; g<10; g++) ss = fmaf(s[(size_t)n*10+g], scale[g*64+f], ss);
  float xvv = x[idx];
  x[idx] = xvv + 0.01f*(xvv*ss + shiftsum[f]);
}

// ---------- readout: pull-based segment sum + relu ----------
__global__ __launch_bounds__(256) void k_gseg(const float* __restrict__ x,
  const int* __restrict__ goff, float* __restrict__ gout)
{
  int lane = threadIdx.x & 63;
  int wid = (blockIdx.x*256 + threadIdx.x) >> 6;
  int nw  = (gridDim.x*256) >> 6;
  for (int g = wid; g < N_GRAPHS; g += nw){
    int n0 = goff[g], n1 = goff[g+1];
    float acc = 0.f;
    for (int n = n0; n < n1; n++) acc += x[(size_t)n*64 + lane];
    gout[(size_t)g*64 + lane] = fmaxf(acc, 0.f);
  }
}

__global__ __launch_bounds__(256) void k_head(const float* __restrict__ y,
  const float* __restrict__ w, const float* __restrict__ b,
  float* __restrict__ out, int N)
{
  int n = blockIdx.x*256 + threadIdx.x;
  if (n >= N) return;
  float acc = b[0];
  const float4* p = (const float4*)(y + (size_t)n*64);
  #pragma unroll
  for (int i=0;i<16;i++){
    float4 v = p[i];
    acc = fmaf(v.x, w[4*i+0], acc);
    acc = fmaf(v.y, w[4*i+1], acc);
    acc = fmaf(v.z, w[4*i+2], acc);
    acc = fmaf(v.w, w[4*i+3], acc);
  }
  out[n] = acc;
}

// ---------- host ----------
extern "C" void kernel_launch(void* const* d_in, const int* in_sizes, int n_in,
                              void* d_out, int out_size, void* d_ws, size_t ws_size,
                              hipStream_t stream) {
  (void)in_sizes; (void)n_in; (void)out_size; (void)ws_size;

  // ----- workspace layout -----
  char* base = (char*)d_ws; size_t off = 0;
  auto A = [&](size_t bytes)->void*{ void* p = base + off; off += (bytes + 255) & ~(size_t)255; return p; };
  unsigned short* e_emb = (unsigned short*)A((size_t)N_EDGES*64*2);   // bf16 e_emb (sorted order)
  float* xbuf   = (float*)A((size_t)N_NODES*64*4);
  float* xl     = (float*)A((size_t)N_NODES*64*4);
  float* xr     = (float*)A((size_t)N_NODES*64*4);
  float* agg    = (float*)A((size_t)N_NODES*64*4);
  int*   perm   = (int*)A((size_t)N_EDGES*4);
  int*   srcp   = (int*)A((size_t)N_EDGES*4);
  int*   segoff = (int*)A((size_t)(N_NODES+1)*4);
  int*   cursor = (int*)A((size_t)N_NODES*4);
  int*   bsum   = (int*)A(512*4);
  int*   bo     = (int*)A(512*4);
  int*   goff   = (int*)A((size_t)(N_GRAPHS+1)*4);
  float* sbuf   = (float*)A((size_t)N_NODES*10*4);
  float* gout   = (float*)A((size_t)N_GRAPHS*64*4);
  float* ybuf   = (float*)A((size_t)N_GRAPHS*64*4);
  float* ybuf2  = (float*)A((size_t)N_GRAPHS*64*4);
  float* colsum = (float*)A(2*640*4); float* colsumsq = colsum + 640;
  float* scale  = (float*)A((640+64)*4); float* shiftsum = scale + 640;
  unsigned short* W1Tb  = (unsigned short*)A(4096*2);
  unsigned short* W2Tb0 = (unsigned short*)A(4096*2);
  unsigned short* W2Tb1 = (unsigned short*)A(4096*2);
  // split-bf16 weights: lin (BT rows 64x64): Wl0,Wl1,Wr0,Wr1,gWl
  unsigned short* LHI[5]; unsigned short* LLO[5];
  for (int i=0;i<5;i++){ LHI[i]=(unsigned short*)A(4096*2); LLO[i]=(unsigned short*)A(4096*2); }
  // split-bf16 GRU weights ([192][64]): ih0,ih1,hh0,hh1,gih,ghh
  unsigned short* GHI[6]; unsigned short* GLO[6];
  for (int i=0;i<6;i++){ GHI[i]=(unsigned short*)A(12288*2); GLO[i]=(unsigned short*)A(12288*2); }
  float* wf     = (float*)A(60000*4);
  size_t wo = 0;
  auto W = [&](size_t n)->float*{ float* p = wf + wo; wo += n; return p; };

  float* pre_nWT = W(64*92);
  float* gnWT[2] = {W(640), W(640)};
  float* gWrT = W(4096);
  float* ggnWT = W(640);
  float* postWT[2] = {W(4096), W(4096)};

  const float* F[48];
  for (int i=0;i<41;i++) F[i] = (const float*)d_in[i];

  // ----- transpose table (fp32 weights still used by scalar kernels) -----
  CvtArgs ca; ca.cnt = 0;
  auto addT = [&](const float* s, float* d, int r, int c){
    ca.e[ca.cnt].s=s; ca.e[ca.cnt].d=d; ca.e[ca.cnt].rows=r; ca.e[ca.cnt].cols=c; ca.cnt++; };

  addT(F[4],  pre_nWT, 92, 64);
  for (int l=0;l<2;l++) addT(F[19] + l*640,  gnWT[l], 64, 10);
  addT(F[25], gWrT, 64, 64);
  addT(F[33], ggnWT, 64, 10);
  for (int l=0;l<2;l++) addT(F[37] + l*4096, postWT[l], 64, 64);

  // ----- split-bf16 table -----
  SpArgs sa; sa.cnt = 0;
  auto addS = [&](const float* s, unsigned short* dhi, unsigned short* dlo, int n, int k, int tr){
    sa.e[sa.cnt].s=s; sa.e[sa.cnt].dhi=dhi; sa.e[sa.cnt].dlo=dlo;
    sa.e[sa.cnt].n=n; sa.e[sa.cnt].k=k; sa.e[sa.cnt].trans=tr; sa.cnt++; };
  for (int l=0;l<2;l++) addS(F[8]  + l*4096, LHI[l],   LLO[l],   64, 64, 1);  // Wl
  for (int l=0;l<2;l++) addS(F[10] + l*4096, LHI[2+l], LLO[2+l], 64, 64, 1);  // Wr
  addS(F[23], LHI[4], LLO[4], 64, 64, 1);                                     // gWl
  for (int l=0;l<2;l++) addS(F[15] + l*12288, GHI[l],   GLO[l],   192, 64, 0); // Wih
  for (int l=0;l<2;l++) addS(F[16] + l*12288, GHI[2+l], GLO[2+l], 192, 64, 0); // Whh
  addS(F[29], GHI[4], GLO[4], 192, 64, 0);                                    // gWih
  addS(F[30], GHI[5], GLO[5], 192, 64, 0);                                    // gWhh

  const int* src   = (const int*)d_in[1];
  const int* dst   = src + N_EDGES;
  const int* batch = (const int*)d_in[3];

  const int NBn = (N_NODES + 255)/256;    // 391
  const int NBg = (N_GRAPHS + 255)/256;   // 4
  const int NBa = (N_NODES*64)/256;       // 25000
  const int NBemb = N_EDGES/64;           // 25000
  const int NBt = (N_NODES + 63)/64;      // 1563 (64-row MFMA tiles)
  const int NBtg = (N_GRAPHS + 63)/64;    // 16

  k_convert<<<dim3(24, ca.cnt), 256, 0, stream>>>(ca);
  k_wsplit<<<dim3(8, sa.cnt), 256, 0, stream>>>(sa);
  k_wprep<<<16,256,0,stream>>>(F[6], F[12], F[12]+4096, W1Tb, W2Tb0, W2Tb1);

  // ----- CSR build (dst-sorted edge list), once per launch -----
  hipMemsetAsync(cursor, 0, (size_t)N_NODES*4, stream);
  k_hist<<<2048,256,0,stream>>>(dst, cursor);
  k_scan1<<<NBn,256,0,stream>>>(cursor, segoff, bsum, N_NODES);
  k_scan2<<<1,512,0,stream>>>(bsum, bo, NBn);
  k_scan3<<<NBn,256,0,stream>>>(segoff, bo, cursor, N_NODES);
  k_scatter<<<2048,256,0,stream>>>(src, dst, cursor, srcp, perm);
  k_goff<<<NBn,256,0,stream>>>(batch, goff);

  // x = relu(x_in @ pre_nW + pre_nb)
  k_linear64<92,1,0,0,1><<<NBn,256,0,stream>>>(F[0], pre_nWT, F[5], xbuf, N_NODES);

  for (int l=0; l<2; l++){
    // e_emb = relu(edge_attr @ pre_eW + pre_eb) @ We[l]   (fused MFMA, bf16, sorted order)
    k_edge_emb<<<NBemb,256,0,stream>>>(F[2], perm, W1Tb, F[7], (l==0)?W2Tb0:W2Tb1, e_emb, N_EDGES);

    for (int t=0; t<2; t++){
      // xl, xr in one fused MFMA pass
      k_lin_mfma<1,0><<<NBt,256,0,stream>>>(xbuf,
          LHI[l], LLO[l], F[9] + l*64, xl,
          LHI[2+l], LLO[2+l], F[11] + l*64, xr, N_NODES);
      k_gat_fused<1,0><<<4096,256,0,stream>>>(srcp, segoff, xl, xr, e_emb,
                                              F[13] + l*64, agg, N_NODES);
      k_gru_mfma<<<NBt,256,0,stream>>>(agg, F[14] + l*64, xbuf,
          GHI[l], GLO[l], GHI[2+l], GLO[2+l],
          F[17] + l*192, F[18] + l*192, N_NODES);
    }
    hipMemsetAsync(colsum, 0, 2*640*4, stream);
    k_dgn_s<<<NBn,256,0,stream>>>(xbuf, gnWT[l], F[20] + l*10, sbuf, N_NODES);
    k_dgn_stats<<<128,640,0,stream>>>(sbuf, xbuf, colsum, colsumsq, N_NODES);
    k_dgn_final<<<1,640,0,stream>>>(colsum, colsumsq, F[21] + l*640, F[22] + l*640, scale, shiftsum, N_NODES);
    k_dgn_apply<<<NBa,256,0,stream>>>(xbuf, sbuf, scale, shiftsum, N_NODES);
  }

  // readout: out = relu(segment_sum(x, batch))  (pull-based, no atomics)
  k_gseg<<<250,256,0,stream>>>(xbuf, goff, gout);

  // xl_g fixed across both timesteps (x doesn't change here)
  k_lin_mfma<0,0><<<NBt,256,0,stream>>>(xbuf, LHI[4], LLO[4], F[24], xl,
                                        nullptr, nullptr, nullptr, nullptr, N_NODES);
  for (int t=0; t<2; t++){
    k_linear64<64,0,0,0,1><<<NBg,256,0,stream>>>(gout, gWrT, F[26], xr, N_GRAPHS);
    k_gat_fused<0,1><<<256,256,0,stream>>>(nullptr, goff, xl, xr, nullptr,
                                           F[27], agg, N_GRAPHS);
    k_gru_mfma<<<NBtg,256,0,stream>>>(agg, F[28], gout,
        GHI[4], GLO[4], GHI[5], GLO[5], F[31], F[32], N_GRAPHS);
  }

  hipMemsetAsync(colsum, 0, 2*640*4, stream);
  k_dgn_s<<<NBg,256,0,stream>>>(gout, ggnWT, F[34], sbuf, N_GRAPHS);
  k_dgn_stats<<<8,640,0,stream>>>(sbuf, gout, colsum, colsumsq, N_GRAPHS);
  k_dgn_final<<<1,640,0,stream>>>(colsum, colsumsq, F[35], F[36], scale, shiftsum, N_GRAPHS);
  k_dgn_apply<<<(N_GRAPHS*64+255)/256,256,0,stream>>>(gout, sbuf, scale, shiftsum, N_GRAPHS);

  // post MLP + head
  k_linear64<64,1,0,0,1><<<NBg,256,0,stream>>>(gout, postWT[0], F[38],      ybuf,  N_GRAPHS);
  k_linear64<64,1,0,0,1><<<NBg,256,0,stream>>>(ybuf, postWT[1], F[38] + 64, ybuf2, N_GRAPHS);
  k_head<<<NBg,256,0,stream>>>(ybuf2, F[39], F[40], (float*)d_out, N_GRAPHS);
}

// Round 5
// 2929.761 us; speedup vs baseline: 3.0145x; 1.3056x over previous
//
#include <hip/hip_runtime.h>
#include <hip/hip_bf16.h>

#define N_NODES 100000
#define N_EDGES 1600000
#define N_GRAPHS 1000
#define HID 64
#define GRP 10

typedef __attribute__((ext_vector_type(8))) short bf16x8;
typedef __attribute__((ext_vector_type(4))) float f32x4;

// ---------- helpers ----------
__device__ __forceinline__ float bf1(unsigned short u){ union{unsigned int x; float f;} v; v.x = ((unsigned int)u)<<16; return v.f; }
__device__ __forceinline__ float bf_lo(unsigned int u){ union{unsigned int x; float f;} v; v.x = u<<16; return v.f; }
__device__ __forceinline__ float bf_hi(unsigned int u){ union{unsigned int x; float f;} v; v.x = u & 0xFFFF0000u; return v.f; }
__device__ __forceinline__ unsigned short f2bf(float f){
  union{float f; unsigned int i;} v; v.f = f;
  unsigned int r = v.i + 0x7FFFu + ((v.i >> 16) & 1u);
  return (unsigned short)(r >> 16);
}
__device__ __forceinline__ float eluf(float v){ return v > 0.f ? v : expm1f(v); }
__device__ __forceinline__ float sigf(float v){ return 1.f/(1.f + expf(-v)); }

// ---------- weight transpose (f32 -> f32) ----------
struct CvtEnt { const float* s; float* d; int rows; int cols; };
struct CvtArgs { CvtEnt e[16]; int cnt; };

__global__ __launch_bounds__(256) void k_convert(CvtArgs a){
  CvtEnt E = a.e[blockIdx.y];
  int n = E.rows * E.cols;
  for (int i = blockIdx.x*256 + threadIdx.x; i < n; i += gridDim.x*256){
    int r = i / E.cols, c = i % E.cols;
    E.d[(size_t)c*E.rows + r] = E.s[i];
  }
}

// ---------- split-bf16 weight prep: dst[n][k] (BT rows), hi/lo pair ----------
struct SpEnt { const float* s; unsigned short* dhi; unsigned short* dlo; int n; int k; int trans; };
struct SpArgs { SpEnt e[12]; int cnt; };

__global__ __launch_bounds__(256) void k_wsplit(SpArgs a){
  SpEnt E = a.e[blockIdx.y];
  int tot = E.n * E.k;
  for (int i = blockIdx.x*256 + threadIdx.x; i < tot; i += gridDim.x*256){
    int nr = i / E.k, kc = i - nr*E.k;
    float v = E.trans ? E.s[(size_t)kc*E.n + nr] : E.s[i];
    unsigned short hi = f2bf(v);
    unsigned short lo = f2bf(v - bf1(hi));
    E.dhi[i] = hi; E.dlo[i] = lo;
  }
}

// bf16 transposed (and K-padded) weights for the MFMA edge-embedding kernel.
__global__ __launch_bounds__(256) void k_wprep(const float* __restrict__ W1,
  const float* __restrict__ W2a, const float* __restrict__ W2b,
  unsigned short* __restrict__ W1Tb, unsigned short* __restrict__ W2Tba,
  unsigned short* __restrict__ W2Tbb)
{
  int i = blockIdx.x*256 + threadIdx.x;   // 0..4095
  if (i >= 4096) return;
  int out = i & 63, k = i >> 6;
  int ks = k < 50 ? k : 0;
  unsigned short v1 = f2bf(W1[ks*64 + out]);
  if (k >= 50) v1 = 0;
  W1Tb [out*64 + k] = v1;
  W2Tba[out*64 + k] = f2bf(W2a[k*64 + out]);
  W2Tbb[out*64 + k] = f2bf(W2b[k*64 + out]);
}

// ---------- CSR build: histogram -> scan -> scatter ----------
__global__ __launch_bounds__(256) void k_hist(const int* __restrict__ dst, int* __restrict__ cnt){
  for (int e = blockIdx.x*256 + threadIdx.x; e < N_EDGES; e += gridDim.x*256)
    atomicAdd(cnt + dst[e], 1);
}

__global__ __launch_bounds__(256) void k_scan1(const int* __restrict__ cnt,
  int* __restrict__ excl, int* __restrict__ bsum, int N)
{
  __shared__ int sh[256];
  int t = threadIdx.x;
  int i = blockIdx.x*256 + t;
  int v = (i < N) ? cnt[i] : 0;
  sh[t] = v;
  __syncthreads();
  #pragma unroll
  for (int o=1;o<256;o<<=1){
    int x = (t>=o) ? sh[t-o] : 0;
    __syncthreads();
    sh[t] += x;
    __syncthreads();
  }
  if (i < N) excl[i] = sh[t] - v;
  if (t == 255) bsum[blockIdx.x] = sh[255];
}

__global__ __launch_bounds__(512) void k_scan2(const int* __restrict__ bsum,
  int* __restrict__ bo, int NB)
{
  __shared__ int sh[512];
  int t = threadIdx.x;
  int v = (t < NB) ? bsum[t] : 0;
  sh[t] = v;
  __syncthreads();
  #pragma unroll
  for (int o=1;o<512;o<<=1){
    int x = (t>=o) ? sh[t-o] : 0;
    __syncthreads();
    sh[t] += x;
    __syncthreads();
  }
  if (t < NB) bo[t] = sh[t] - v;
}

__global__ __launch_bounds__(256) void k_scan3(int* __restrict__ segoff,
  const int* __restrict__ bo, int* __restrict__ cursor, int N)
{
  int i = blockIdx.x*256 + threadIdx.x;
  if (i >= N) return;
  int v = segoff[i] + bo[i>>8];
  segoff[i] = v;
  cursor[i] = v;
  if (i == 0) segoff[N] = N_EDGES;
}

__global__ __launch_bounds__(256) void k_scatter(const int* __restrict__ src,
  const int* __restrict__ dst, int* __restrict__ cursor,
  int* __restrict__ srcp, int* __restrict__ perm)
{
  for (int e = blockIdx.x*256 + threadIdx.x; e < N_EDGES; e += gridDim.x*256){
    int d = dst[e];
    int pos = atomicAdd(cursor + d, 1);
    srcp[pos] = src[e];
    perm[pos] = e;
  }
}

// graph segment offsets from sorted batch array
__global__ __launch_bounds__(256) void k_goff(const int* __restrict__ batch, int* __restrict__ goff){
  for (int n = blockIdx.x*256 + threadIdx.x; n < N_NODES; n += gridDim.x*256){
    int b = batch[n];
    int prev = (n==0) ? -1 : batch[n-1];
    for (int g = prev+1; g <= b; g++) goff[g] = n;
    if (n == N_NODES-1){ for (int g=b+1; g<=N_GRAPHS; g++) goff[g] = N_NODES; }
  }
}

// ---------- fused MFMA edge embedding ----------
// persistent grid-stride blocks; weights hoisted; register-staged gather
// pipelined one tile ahead (issue t+1's loads before computing t).
__global__ __launch_bounds__(256) void k_edge_emb(
  const float* __restrict__ EA, const int* __restrict__ perm,
  const unsigned short* __restrict__ W1Tb,
  const float* __restrict__ b1, const unsigned short* __restrict__ W2Tb,
  unsigned short* __restrict__ out, int nTiles)
{
  __shared__ float ea[64*50];              // fp32 input tile
  __shared__ unsigned short hb[64*72];     // hidden tile, reused as out staging

  int tid = threadIdx.x;
  int lane = tid & 63;
  int wave = tid >> 6;
  int row16 = lane & 15;
  int kg = lane >> 4;

  // weight fragments hoisted (loaded once per block)
  bf16x8 w1[4][2], w2[4][2];
  #pragma unroll
  for (int n=0;n<4;n++){
    #pragma unroll
    for (int kk=0;kk<2;kk++){
      w1[n][kk] = *(const bf16x8*)(W1Tb + (n*16+row16)*64 + kk*32 + kg*8);
      w2[n][kk] = *(const bf16x8*)(W2Tb + (n*16+row16)*64 + kk*32 + kg*8);
    }
  }
  float bias[4];
  #pragma unroll
  for (int n=0;n<4;n++) bias[n] = b1[n*16+row16];

  int r = wave*16 + row16;
  float2 st[7];

  // prologue: issue gather for first tile
  {
    long tile = blockIdx.x;
    if (tile < nTiles){
      #pragma unroll
      for (int k=0;k<7;k++){
        int j = tid + (k<<8);
        if (j < 1600){
          int row = j/25, c2 = j - row*25;
          int p = perm[tile*64 + row];
          st[k] = *(const float2*)(EA + (size_t)p*50 + (c2<<1));
        }
      }
    }
  }

  for (long t = blockIdx.x; t < nTiles; t += gridDim.x){
    // commit staged gather (t) to LDS
    #pragma unroll
    for (int k=0;k<7;k++){
      int j = tid + (k<<8);
      if (j < 1600){
        int row = j/25, c2 = j - row*25;
        *(float2*)(ea + row*50 + (c2<<1)) = st[k];
      }
    }
    __syncthreads();
    // issue gather for t+gridDim (overlaps with compute below)
    long tn = t + gridDim.x;
    if (tn < nTiles){
      #pragma unroll
      for (int k=0;k<7;k++){
        int j = tid + (k<<8);
        if (j < 1600){
          int row = j/25, c2 = j - row*25;
          int p = perm[tn*64 + row];
          st[k] = *(const float2*)(EA + (size_t)p*50 + (c2<<1));
        }
      }
    }

    // stage1 A-frags (fp32 -> bf16 in-register)
    bf16x8 a0, a1;
    {
      const float* p = ea + r*50;
      #pragma unroll
      for (int i=0;i<8;i++) ((short*)&a0)[i] = (short)f2bf(p[kg*8+i]);
      #pragma unroll
      for (int i=0;i<8;i++){
        int k = 32 + kg*8 + i;
        ((short*)&a1)[i] = (short)((k < 50) ? f2bf(p[k]) : (unsigned short)0);
      }
    }
    f32x4 c[4];
    #pragma unroll
    for (int n=0;n<4;n++){
      f32x4 acc = {0.f,0.f,0.f,0.f};
      acc = __builtin_amdgcn_mfma_f32_16x16x32_bf16(a0, w1[n][0], acc, 0,0,0);
      acc = __builtin_amdgcn_mfma_f32_16x16x32_bf16(a1, w1[n][1], acc, 0,0,0);
      c[n] = acc;
    }
    // bias + relu, h -> LDS (bf16)
    #pragma unroll
    for (int n=0;n<4;n++){
      #pragma unroll
      for (int q=0;q<4;q++){
        float v = fmaxf(c[n][q] + bias[n], 0.f);
        hb[(wave*16 + kg*4 + q)*72 + n*16 + row16] = f2bf(v);
      }
    }
    __syncthreads();

    // stage2 A-frags from LDS
    bf16x8 ha = *(const bf16x8*)(hb + r*72 + kg*8);
    bf16x8 hc = *(const bf16x8*)(hb + r*72 + 32 + kg*8);
    f32x4 d[4];
    #pragma unroll
    for (int n=0;n<4;n++){
      f32x4 acc = {0.f,0.f,0.f,0.f};
      acc = __builtin_amdgcn_mfma_f32_16x16x32_bf16(ha, w2[n][0], acc, 0,0,0);
      acc = __builtin_amdgcn_mfma_f32_16x16x32_bf16(hc, w2[n][1], acc, 0,0,0);
      d[n] = acc;
    }
    __syncthreads();          // all hb reads done -> reuse as out staging
    #pragma unroll
    for (int n=0;n<4;n++){
      #pragma unroll
      for (int q=0;q<4;q++)
        hb[(wave*16 + kg*4 + q)*72 + n*16 + row16] = f2bf(d[n][q]);
    }
    __syncthreads();

    // coalesced store: 64 rows x 128B, thread t handles 32B
    {
      int rr = tid >> 2, q = tid & 3;
      const uint4* sp = (const uint4*)(hb + rr*72 + (q<<4));
      uint4 v0 = sp[0], v1 = sp[1];
      uint4* gp = (uint4*)(out + (t*64 + rr)*64 + (q<<4));
      gp[0] = v0; gp[1] = v1;
    }
    // loop-top barrier (after ea commit) orders hb reads vs next writes
  }
}

// ---------- split-bf16 staging helper: write hi/lo 4-short packs ----------
__device__ __forceinline__ void pack4(unsigned short* hi, unsigned short* lo, int ofs,
                                      float v0, float v1, float v2, float v3){
  unsigned short h0=f2bf(v0), h1=f2bf(v1), h2=f2bf(v2), h3=f2bf(v3);
  unsigned short l0=f2bf(v0-bf1(h0)), l1=f2bf(v1-bf1(h1)), l2=f2bf(v2-bf1(h2)), l3=f2bf(v3-bf1(h3));
  uint2 ph, pl;
  ph.x = ((unsigned int)h1<<16)|h0; ph.y = ((unsigned int)h3<<16)|h2;
  pl.x = ((unsigned int)l1<<16)|l0; pl.y = ((unsigned int)l3<<16)|l2;
  *(uint2*)(hi + ofs) = ph;
  *(uint2*)(lo + ofs) = pl;
}

// ---------- MFMA linear (split-bf16, ~fp32 accurate): out = X@W + b, optional dual output ----------
template<int DUAL, int RELU>
__global__ __launch_bounds__(256) void k_lin_mfma(
  const float* __restrict__ X,
  const unsigned short* __restrict__ WAhi, const unsigned short* __restrict__ WAlo,
  const float* __restrict__ bA, float* __restrict__ outA,
  const unsigned short* __restrict__ WBhi, const unsigned short* __restrict__ WBlo,
  const float* __restrict__ bB, float* __restrict__ outB, int N)
{
  __shared__ unsigned short xh[64*72], xlo[64*72];
  int tid = threadIdx.x, lane = tid & 63, wave = tid >> 6;
  int col = lane & 15, kg = lane >> 4;
  long base = (long)blockIdx.x * 64;

  for (int idx = tid; idx < 1024; idx += 256){
    int r = idx >> 4, q = idx & 15;
    long row = base + r;
    float4 v = {0,0,0,0};
    if (row < N) v = ((const float4*)X)[row*16 + q];
    pack4(xh, xlo, r*72 + q*4, v.x, v.y, v.z, v.w);
  }
  __syncthreads();

  int r = wave*16 + col;
  bf16x8 ah[2], al[2];
  ah[0] = *(const bf16x8*)(xh  + r*72 + kg*8);
  ah[1] = *(const bf16x8*)(xh  + r*72 + 32 + kg*8);
  al[0] = *(const bf16x8*)(xlo + r*72 + kg*8);
  al[1] = *(const bf16x8*)(xlo + r*72 + 32 + kg*8);

  #pragma unroll
  for (int ct = 0; ct < 4; ct++){
    f32x4 aA = {0,0,0,0}, aB = {0,0,0,0};
    #pragma unroll
    for (int kk = 0; kk < 2; kk++){
      int wofs = (ct*16 + col)*64 + kk*32 + kg*8;
      bf16x8 bh = *(const bf16x8*)(WAhi + wofs);
      bf16x8 bl = *(const bf16x8*)(WAlo + wofs);
      aA = __builtin_amdgcn_mfma_f32_16x16x32_bf16(ah[kk], bh, aA, 0,0,0);
      aA = __builtin_amdgcn_mfma_f32_16x16x32_bf16(al[kk], bh, aA, 0,0,0);
      aA = __builtin_amdgcn_mfma_f32_16x16x32_bf16(ah[kk], bl, aA, 0,0,0);
      if (DUAL){
        bf16x8 ch = *(const bf16x8*)(WBhi + wofs);
        bf16x8 cl = *(const bf16x8*)(WBlo + wofs);
        aB = __builtin_amdgcn_mfma_f32_16x16x32_bf16(ah[kk], ch, aB, 0,0,0);
        aB = __builtin_amdgcn_mfma_f32_16x16x32_bf16(al[kk], ch, aB, 0,0,0);
        aB = __builtin_amdgcn_mfma_f32_16x16x32_bf16(ah[kk], cl, aB, 0,0,0);
      }
    }
    int c = ct*16 + col;
    float bAv = bA[c];
    float bBv = DUAL ? bB[c] : 0.f;
    #pragma unroll
    for (int reg = 0; reg < 4; reg++){
      long gr = base + wave*16 + kg*4 + reg;
      if (gr < N){
        float vA = aA[reg] + bAv;
        if (RELU) vA = fmaxf(vA, 0.f);
        outA[gr*64 + c] = vA;
        if (DUAL){
          float vB = aB[reg] + bBv;
          if (RELU) vB = fmaxf(vB, 0.f);
          outB[gr*64 + c] = vB;
        }
      }
    }
  }
}

// ---------- MFMA GRU: h = elu(agg+gatb); x = relu(gru(h, x)) in-place ----------
__global__ __launch_bounds__(256) void k_gru_mfma(
  const float* __restrict__ agg, const float* __restrict__ gatb,
  float* __restrict__ x,
  const unsigned short* __restrict__ Wih_hi, const unsigned short* __restrict__ Wih_lo,
  const unsigned short* __restrict__ Whh_hi, const unsigned short* __restrict__ Whh_lo,
  const float* __restrict__ bih, const float* __restrict__ bhh, int N)
{
  __shared__ unsigned short hh_[64*72], hl_[64*72], xh_[64*72], xl_[64*72];
  int tid = threadIdx.x, lane = tid & 63, wave = tid >> 6;
  int col = lane & 15, kg = lane >> 4;
  long base = (long)blockIdx.x * 64;

  for (int idx = tid; idx < 1024; idx += 256){
    int r = idx >> 4, q = idx & 15;
    long row = base + r;
    float4 a = {0,0,0,0}, xx = {0,0,0,0};
    if (row < N){
      a  = ((const float4*)agg)[row*16 + q];
      xx = ((const float4*)x)[row*16 + q];
    }
    float h0 = eluf(a.x + gatb[q*4+0]);
    float h1 = eluf(a.y + gatb[q*4+1]);
    float h2 = eluf(a.z + gatb[q*4+2]);
    float h3 = eluf(a.w + gatb[q*4+3]);
    pack4(hh_, hl_, r*72 + q*4, h0, h1, h2, h3);
    pack4(xh_, xl_, r*72 + q*4, xx.x, xx.y, xx.z, xx.w);
  }
  __syncthreads();

  int r = wave*16 + col;
  bf16x8 hhi[2], hlo[2], xhi[2], xlo2[2];
  hhi[0] = *(const bf16x8*)(hh_ + r*72 + kg*8);
  hhi[1] = *(const bf16x8*)(hh_ + r*72 + 32 + kg*8);
  hlo[0] = *(const bf16x8*)(hl_ + r*72 + kg*8);
  hlo[1] = *(const bf16x8*)(hl_ + r*72 + 32 + kg*8);
  xhi[0] = *(const bf16x8*)(xh_ + r*72 + kg*8);
  xhi[1] = *(const bf16x8*)(xh_ + r*72 + 32 + kg*8);
  xlo2[0] = *(const bf16x8*)(xl_ + r*72 + kg*8);
  xlo2[1] = *(const bf16x8*)(xl_ + r*72 + 32 + kg*8);

  #pragma unroll
  for (int ct = 0; ct < 4; ct++){
    f32x4 ai[3], ah[3];
    #pragma unroll
    for (int g=0; g<3; g++){ ai[g] = (f32x4){0,0,0,0}; ah[g] = (f32x4){0,0,0,0}; }
    #pragma unroll
    for (int g = 0; g < 3; g++){
      int nt = g*4 + ct;
      #pragma unroll
      for (int kk = 0; kk < 2; kk++){
        int wofs = (nt*16 + col)*64 + kk*32 + kg*8;
        bf16x8 bh = *(const bf16x8*)(Wih_hi + wofs);
        bf16x8 bl = *(const bf16x8*)(Wih_lo + wofs);
        ai[g] = __builtin_amdgcn_mfma_f32_16x16x32_bf16(hhi[kk], bh, ai[g], 0,0,0);
        ai[g] = __builtin_amdgcn_mfma_f32_16x16x32_bf16(hlo[kk], bh, ai[g], 0,0,0);
        ai[g] = __builtin_amdgcn_mfma_f32_16x16x32_bf16(hhi[kk], bl, ai[g], 0,0,0);
        bf16x8 ch = *(const bf16x8*)(Whh_hi + wofs);
        bf16x8 cl = *(const bf16x8*)(Whh_lo + wofs);
        ah[g] = __builtin_amdgcn_mfma_f32_16x16x32_bf16(xhi[kk], ch, ah[g], 0,0,0);
        ah[g] = __builtin_amdgcn_mfma_f32_16x16x32_bf16(xlo2[kk], ch, ah[g], 0,0,0);
        ah[g] = __builtin_amdgcn_mfma_f32_16x16x32_bf16(xhi[kk], cl, ah[g], 0,0,0);
      }
    }
    int c = ct*16 + col;
    float bi0 = bih[c], bi1 = bih[64+c], bi2 = bih[128+c];
    float bh0 = bhh[c], bh1 = bhh[64+c], bh2 = bhh[128+c];
    #pragma unroll
    for (int reg = 0; reg < 4; reg++){
      int rr = wave*16 + kg*4 + reg;
      long gr = base + rr;
      float ir = ai[0][reg] + bi0, iz = ai[1][reg] + bi1, in2 = ai[2][reg] + bi2;
      float hr = ah[0][reg] + bh0, hz = ah[1][reg] + bh1, hn = ah[2][reg] + bh2;
      float xv = bf1(xh_[rr*72 + c]) + bf1(xl_[rr*72 + c]);
      float r_ = sigf(ir + hr);
      float z  = sigf(iz + hz);
      float nn = tanhf(in2 + r_*hn);
      float o = (1.f - z)*nn + z*xv;
      if (gr < N) x[gr*64 + c] = fmaxf(o, 0.f);
    }
  }
}

// ---------- generic linear: out[n,0..63] = act(A[n,:] @ W + b) ----------
template<int K, int RELU, int INBF, int OUTBF, int HASB>
__global__ __launch_bounds__(256) void k_linear64(const void* Ap,
    const float* __restrict__ WT, const float* __restrict__ bias, void* Op, int N)
{
  int n = blockIdx.x*256 + threadIdx.x;
  if (n >= N) return;
  float a[K];
  if constexpr (INBF){
    const unsigned int* p = (const unsigned int*)((const unsigned short*)Ap + (size_t)n*K);
    #pragma unroll
    for (int i=0;i<K/2;i++){ unsigned int u=p[i]; a[2*i]=bf_lo(u); a[2*i+1]=bf_hi(u); }
  } else if constexpr (K % 4 == 0){
    const float4* p = (const float4*)((const float*)Ap + (size_t)n*K);
    #pragma unroll
    for (int i=0;i<K/4;i++){ float4 v=p[i]; a[4*i]=v.x; a[4*i+1]=v.y; a[4*i+2]=v.z; a[4*i+3]=v.w; }
  } else {
    const float2* p = (const float2*)((const float*)Ap + (size_t)n*K);
    #pragma unroll
    for (int i=0;i<K/2;i++){ float2 v=p[i]; a[2*i]=v.x; a[2*i+1]=v.y; }
  }
  for (int c=0;c<64;c+=4){
    float s0 = HASB ? bias[c+0] : 0.f;
    float s1 = HASB ? bias[c+1] : 0.f;
    float s2 = HASB ? bias[c+2] : 0.f;
    float s3 = HASB ? bias[c+3] : 0.f;
    const float* w = WT + (size_t)c*K;
    #pragma unroll
    for (int k=0;k<K;k++){
      float av = a[k];
      s0 = fmaf(av, w[k],     s0);
      s1 = fmaf(av, w[K+k],   s1);
      s2 = fmaf(av, w[2*K+k], s2);
      s3 = fmaf(av, w[3*K+k], s3);
    }
    if (RELU){ s0=fmaxf(s0,0.f); s1=fmaxf(s1,0.f); s2=fmaxf(s2,0.f); s3=fmaxf(s3,0.f); }
    if constexpr (OUTBF){
      uint2 uu;
      uu.x = ((unsigned int)f2bf(s1)<<16) | f2bf(s0);
      uu.y = ((unsigned int)f2bf(s3)<<16) | f2bf(s2);
      *(uint2*)((unsigned short*)Op + (size_t)n*64 + c) = uu;
    } else {
      float4 r; r.x=s0; r.y=s1; r.z=s2; r.w=s3;
      *(float4*)((float*)Op + (size_t)n*64 + c) = r;
    }
  }
}

// ---------- fused GATv2 attention+aggregate (pull-based, online softmax, 2-way unrolled) ----------
template<int HASEMB, int IDSRC>
__global__ __launch_bounds__(256) void k_gat_fused(
  const int* __restrict__ srcp, const int* __restrict__ segoff,
  const float* __restrict__ xl, const float* __restrict__ xr,
  const unsigned short* __restrict__ emb, const float* __restrict__ att,
  float* __restrict__ agg, int nseg)
{
  int lane = threadIdx.x & 63;
  float av = att[lane];
  int wid = (blockIdx.x*256 + threadIdx.x) >> 6;
  int nw  = (gridDim.x*256) >> 6;
  for (int d = wid; d < nseg; d += nw){
    int e0 = segoff[d], e1 = segoff[d+1];
    float xrv = xr[(size_t)d*64 + lane];
    float m = -3.0e38f, s = 0.f, acc = 0.f;
    int e = e0;
    for (; e + 2 <= e1; e += 2){
      int sA = IDSRC ? e   : srcp[e];
      int sB = IDSRC ? e+1 : srcp[e+1];
      float xsA = xl[(size_t)sA*64 + lane];
      float xsB = xl[(size_t)sB*64 + lane];
      float vA = xsA + xrv, vB = xsB + xrv;
      if (HASEMB){
        vA += bf1(emb[(size_t)e*64 + lane]);
        vB += bf1(emb[(size_t)(e+1)*64 + lane]);
      }
      vA = vA > 0.f ? vA : 0.01f*vA;
      vB = vB > 0.f ? vB : 0.01f*vB;
      float pA = vA * av, pB = vB * av;
      #pragma unroll
      for (int o=32;o;o>>=1){ pA += __shfl_xor(pA, o, 64); pB += __shfl_xor(pB, o, 64); }
      float mn = fmaxf(m, fmaxf(pA, pB));
      float cm = expf(m - mn);
      float cA = expf(pA - mn);
      float cB = expf(pB - mn);
      s = fmaf(s, cm, cA + cB);
      acc = fmaf(acc, cm, fmaf(cA, xsA, cB*xsB));
      m = mn;
    }
    if (e < e1){
      int sN = IDSRC ? e : srcp[e];
      float xs = xl[(size_t)sN*64 + lane];
      float v = xs + xrv;
      if (HASEMB) v += bf1(emb[(size_t)e*64 + lane]);
      v = v > 0.f ? v : 0.01f*v;
      float p = v * av;
      #pragma unroll
      for (int o=32;o;o>>=1) p += __shfl_xor(p, o, 64);
      float mn = fmaxf(m, p);
      float cm = expf(m - mn);
      float cp = expf(p - mn);
      s   = fmaf(s, cm, cp);
      acc = fmaf(acc, cm, cp*xs);
      m = mn;
    }
    agg[(size_t)d*64 + lane] = acc / (s + 1e-16f);
  }
}

// ---------- DiffGroupNorm ----------
__global__ __launch_bounds__(256) void k_dgn_s(const float* __restrict__ x,
  const float* __restrict__ WT /*10x64*/, const float* __restrict__ b,
  float* __restrict__ s, int N)
{
  int n = blockIdx.x*256 + threadIdx.x;
  if (n >= N) return;
  float a[64];
  const float4* p = (const float4*)(x + (size_t)n*64);
  #pragma unroll
  for (int i=0;i<16;i++){ float4 v=p[i]; a[4*i]=v.x; a[4*i+1]=v.y; a[4*i+2]=v.z; a[4*i+3]=v.w; }
  float lg[10];
  #pragma unroll
  for (int g=0; g<10; g++){
    float acc = b[g];
    const float* w = WT + (size_t)g*64;
    #pragma unroll
    for (int k=0;k<64;k++) acc = fmaf(a[k], w[k], acc);
    lg[g] = acc;
  }
  float m = lg[0];
  #pragma unroll
  for (int g=1;g<10;g++) m = fmaxf(m, lg[g]);
  float e[10], sum = 0.f;
  #pragma unroll
  for (int g=0;g<10;g++){ e[g] = expf(lg[g]-m); sum += e[g]; }
  float inv = 1.f/sum;
  #pragma unroll
  for (int g=0;g<10;g++) s[(size_t)n*10+g] = e[g]*inv;
}

__global__ __launch_bounds__(640) void k_dgn_stats(const float* __restrict__ s,
  const float* __restrict__ x, float* cs, float* cs2, int N)
{
  int g = threadIdx.x >> 6, f = threadIdx.x & 63;
  int per = (N + gridDim.x - 1) / gridDim.x;
  int n0 = blockIdx.x * per;
  int n1 = min(N, n0 + per);
  float a = 0.f, a2 = 0.f;
  for (int n = n0; n < n1; n++){
    float y = s[(size_t)n*10+g] * x[(size_t)n*64+f];
    a += y; a2 += y*y;
  }
  atomicAdd(&cs [g*64+f], a);
  atomicAdd(&cs2[g*64+f], a2);
}

__global__ void k_dgn_final(const float* cs, const float* cs2,
  const float* __restrict__ bw, const float* __restrict__ bb,
  float* scale, float* shiftsum, int N)
{
  __shared__ float sh[640];
  int i = threadIdx.x;
  float invN = 1.f / (float)N;
  float mean = cs[i]*invN;
  float var  = cs2[i]*invN - mean*mean;
  float sc = bw[i] / sqrtf(var + 1e-5f);
  scale[i] = sc;
  sh[i] = bb[i] - mean*sc;
  __syncthreads();
  if (i < 64){
    float t = 0.f;
    #pragma unroll
    for (int g=0;g<10;g++) t += sh[g*64+i];
    shiftsum[i] = t;
  }
}

__global__ __launch_bounds__(256) void k_dgn_apply(float* x,
  const float* __restrict__ s, const float* __restrict__ scale,
  const float* __restrict__ shiftsum, int N)
{
  int idx = blockIdx.x*256 + threadIdx.x;
  if (idx >= N*64) return;
  int n = idx >> 6, f = idx & 63;
  float ss = 0.f;
  #pragma unroll
  for (int g=0; g<10; g++) ss = fmaf(s[(size_t)n*10+g], scale[g*64+f], ss);
  float xvv = x[idx];
  x[idx] = xvv + 0.01f*(xvv*ss + shiftsum[f]);
}

// ---------- readout: pull-based segment sum + relu ----------
__global__ __launch_bounds__(256) void k_gseg(const float* __restrict__ x,
  const int* __restrict__ goff, float* __restrict__ gout)
{
  int lane = threadIdx.x & 63;
  int wid = (blockIdx.x*256 + threadIdx.x) >> 6;
  int nw  = (gridDim.x*256) >> 6;
  for (int g = wid; g < N_GRAPHS; g += nw){
    int n0 = goff[g], n1 = goff[g+1];
    float acc = 0.f;
    for (int n = n0; n < n1; n++) acc += x[(size_t)n*64 + lane];
    gout[(size_t)g*64 + lane] = fmaxf(acc, 0.f);
  }
}

__global__ __launch_bounds__(256) void k_head(const float* __restrict__ y,
  const float* __restrict__ w, const float* __restrict__ b,
  float* __restrict__ out, int N)
{
  int n = blockIdx.x*256 + threadIdx.x;
  if (n >= N) return;
  float acc = b[0];
  const float4* p = (const float4*)(y + (size_t)n*64);
  #pragma unroll
  for (int i=0;i<16;i++){
    float4 v = p[i];
    acc = fmaf(v.x, w[4*i+0], acc);
    acc = fmaf(v.y, w[4*i+1], acc);
    acc = fmaf(v.z, w[4*i+2], acc);
    acc = fmaf(v.w, w[4*i+3], acc);
  }
  out[n] = acc;
}

// ---------- host ----------
extern "C" void kernel_launch(void* const* d_in, const int* in_sizes, int n_in,
                              void* d_out, int out_size, void* d_ws, size_t ws_size,
                              hipStream_t stream) {
  (void)in_sizes; (void)n_in; (void)out_size; (void)ws_size;

  // ----- workspace layout -----
  char* base = (char*)d_ws; size_t off = 0;
  auto A = [&](size_t bytes)->void*{ void* p = base + off; off += (bytes + 255) & ~(size_t)255; return p; };
  unsigned short* e_emb = (unsigned short*)A((size_t)N_EDGES*64*2);   // bf16 e_emb (sorted order)
  float* xbuf   = (float*)A((size_t)N_NODES*64*4);
  float* xl     = (float*)A((size_t)N_NODES*64*4);
  float* xr     = (float*)A((size_t)N_NODES*64*4);
  float* agg    = (float*)A((size_t)N_NODES*64*4);
  int*   perm   = (int*)A((size_t)N_EDGES*4);
  int*   srcp   = (int*)A((size_t)N_EDGES*4);
  int*   segoff = (int*)A((size_t)(N_NODES+1)*4);
  int*   cursor = (int*)A((size_t)N_NODES*4);
  int*   bsum   = (int*)A(512*4);
  int*   bo     = (int*)A(512*4);
  int*   goff   = (int*)A((size_t)(N_GRAPHS+1)*4);
  float* sbuf   = (float*)A((size_t)N_NODES*10*4);
  float* gout   = (float*)A((size_t)N_GRAPHS*64*4);
  float* ybuf   = (float*)A((size_t)N_GRAPHS*64*4);
  float* ybuf2  = (float*)A((size_t)N_GRAPHS*64*4);
  float* colsum = (float*)A(2*640*4); float* colsumsq = colsum + 640;
  float* scale  = (float*)A((640+64)*4); float* shiftsum = scale + 640;
  unsigned short* W1Tb  = (unsigned short*)A(4096*2);
  unsigned short* W2Tb0 = (unsigned short*)A(4096*2);
  unsigned short* W2Tb1 = (unsigned short*)A(4096*2);
  // split-bf16 weights: lin (BT rows 64x64): Wl0,Wl1,Wr0,Wr1,gWl
  unsigned short* LHI[5]; unsigned short* LLO[5];
  for (int i=0;i<5;i++){ LHI[i]=(unsigned short*)A(4096*2); LLO[i]=(unsigned short*)A(4096*2); }
  // split-bf16 GRU weights ([192][64]): ih0,ih1,hh0,hh1,gih,ghh
  unsigned short* GHI[6]; unsigned short* GLO[6];
  for (int i=0;i<6;i++){ GHI[i]=(unsigned short*)A(12288*2); GLO[i]=(unsigned short*)A(12288*2); }
  float* wf     = (float*)A(60000*4);
  size_t wo = 0;
  auto W = [&](size_t n)->float*{ float* p = wf + wo; wo += n; return p; };

  float* pre_nWT = W(64*92);
  float* gnWT[2] = {W(640), W(640)};
  float* gWrT = W(4096);
  float* ggnWT = W(640);
  float* postWT[2] = {W(4096), W(4096)};

  const float* F[48];
  for (int i=0;i<41;i++) F[i] = (const float*)d_in[i];

  // ----- transpose table (fp32 weights still used by scalar kernels) -----
  CvtArgs ca; ca.cnt = 0;
  auto addT = [&](const float* s, float* d, int r, int c){
    ca.e[ca.cnt].s=s; ca.e[ca.cnt].d=d; ca.e[ca.cnt].rows=r; ca.e[ca.cnt].cols=c; ca.cnt++; };

  addT(F[4],  pre_nWT, 92, 64);
  for (int l=0;l<2;l++) addT(F[19] + l*640,  gnWT[l], 64, 10);
  addT(F[25], gWrT, 64, 64);
  addT(F[33], ggnWT, 64, 10);
  for (int l=0;l<2;l++) addT(F[37] + l*4096, postWT[l], 64, 64);

  // ----- split-bf16 table -----
  SpArgs sa; sa.cnt = 0;
  auto addS = [&](const float* s, unsigned short* dhi, unsigned short* dlo, int n, int k, int tr){
    sa.e[sa.cnt].s=s; sa.e[sa.cnt].dhi=dhi; sa.e[sa.cnt].dlo=dlo;
    sa.e[sa.cnt].n=n; sa.e[sa.cnt].k=k; sa.e[sa.cnt].trans=tr; sa.cnt++; };
  for (int l=0;l<2;l++) addS(F[8]  + l*4096, LHI[l],   LLO[l],   64, 64, 1);  // Wl
  for (int l=0;l<2;l++) addS(F[10] + l*4096, LHI[2+l], LLO[2+l], 64, 64, 1);  // Wr
  addS(F[23], LHI[4], LLO[4], 64, 64, 1);                                     // gWl
  for (int l=0;l<2;l++) addS(F[15] + l*12288, GHI[l],   GLO[l],   192, 64, 0); // Wih
  for (int l=0;l<2;l++) addS(F[16] + l*12288, GHI[2+l], GLO[2+l], 192, 64, 0); // Whh
  addS(F[29], GHI[4], GLO[4], 192, 64, 0);                                    // gWih
  addS(F[30], GHI[5], GLO[5], 192, 64, 0);                                    // gWhh

  const int* src   = (const int*)d_in[1];
  const int* dst   = src + N_EDGES;
  const int* batch = (const int*)d_in[3];

  const int NBn = (N_NODES + 255)/256;    // 391
  const int NBg = (N_GRAPHS + 255)/256;   // 4
  const int NBa = (N_NODES*64)/256;       // 25000
  const int NTIL = N_EDGES/64;            // 25000 tiles
  const int NBt = (N_NODES + 63)/64;      // 1563 (64-row MFMA tiles)
  const int NBtg = (N_GRAPHS + 63)/64;    // 16

  k_convert<<<dim3(24, ca.cnt), 256, 0, stream>>>(ca);
  k_wsplit<<<dim3(8, sa.cnt), 256, 0, stream>>>(sa);
  k_wprep<<<16,256,0,stream>>>(F[6], F[12], F[12]+4096, W1Tb, W2Tb0, W2Tb1);

  // ----- CSR build (dst-sorted edge list), once per launch -----
  hipMemsetAsync(cursor, 0, (size_t)N_NODES*4, stream);
  k_hist<<<2048,256,0,stream>>>(dst, cursor);
  k_scan1<<<NBn,256,0,stream>>>(cursor, segoff, bsum, N_NODES);
  k_scan2<<<1,512,0,stream>>>(bsum, bo, NBn);
  k_scan3<<<NBn,256,0,stream>>>(segoff, bo, cursor, N_NODES);
  k_scatter<<<2048,256,0,stream>>>(src, dst, cursor, srcp, perm);
  k_goff<<<NBn,256,0,stream>>>(batch, goff);

  // x = relu(x_in @ pre_nW + pre_nb)
  k_linear64<92,1,0,0,1><<<NBn,256,0,stream>>>(F[0], pre_nWT, F[5], xbuf, N_NODES);

  for (int l=0; l<2; l++){
    // e_emb = relu(edge_attr @ pre_eW + pre_eb) @ We[l]   (fused MFMA, pipelined gather)
    k_edge_emb<<<4096,256,0,stream>>>(F[2], perm, W1Tb, F[7], (l==0)?W2Tb0:W2Tb1, e_emb, NTIL);

    for (int t=0; t<2; t++){
      // xl, xr in one fused MFMA pass
      k_lin_mfma<1,0><<<NBt,256,0,stream>>>(xbuf,
          LHI[l], LLO[l], F[9] + l*64, xl,
          LHI[2+l], LLO[2+l], F[11] + l*64, xr, N_NODES);
      k_gat_fused<1,0><<<4096,256,0,stream>>>(srcp, segoff, xl, xr, e_emb,
                                              F[13] + l*64, agg, N_NODES);
      k_gru_mfma<<<NBt,256,0,stream>>>(agg, F[14] + l*64, xbuf,
          GHI[l], GLO[l], GHI[2+l], GLO[2+l],
          F[17] + l*192, F[18] + l*192, N_NODES);
    }
    hipMemsetAsync(colsum, 0, 2*640*4, stream);
    k_dgn_s<<<NBn,256,0,stream>>>(xbuf, gnWT[l], F[20] + l*10, sbuf, N_NODES);
    k_dgn_stats<<<512,640,0,stream>>>(sbuf, xbuf, colsum, colsumsq, N_NODES);
    k_dgn_final<<<1,640,0,stream>>>(colsum, colsumsq, F[21] + l*640, F[22] + l*640, scale, shiftsum, N_NODES);
    k_dgn_apply<<<NBa,256,0,stream>>>(xbuf, sbuf, scale, shiftsum, N_NODES);
  }

  // readout: out = relu(segment_sum(x, batch))  (pull-based, no atomics)
  k_gseg<<<250,256,0,stream>>>(xbuf, goff, gout);

  // xl_g fixed across both timesteps (x doesn't change here)
  k_lin_mfma<0,0><<<NBt,256,0,stream>>>(xbuf, LHI[4], LLO[4], F[24], xl,
                                        nullptr, nullptr, nullptr, nullptr, N_NODES);
  for (int t=0; t<2; t++){
    k_linear64<64,0,0,0,1><<<NBg,256,0,stream>>>(gout, gWrT, F[26], xr, N_GRAPHS);
    k_gat_fused<0,1><<<256,256,0,stream>>>(nullptr, goff, xl, xr, nullptr,
                                           F[27], agg, N_GRAPHS);
    k_gru_mfma<<<NBtg,256,0,stream>>>(agg, F[28], gout,
        GHI[4], GLO[4], GHI[5], GLO[5], F[31], F[32], N_GRAPHS);
  }

  hipMemsetAsync(colsum, 0, 2*640*4, stream);
  k_dgn_s<<<NBg,256,0,stream>>>(gout, ggnWT, F[34], sbuf, N_GRAPHS);
  k_dgn_stats<<<8,640,0,stream>>>(sbuf, gout, colsum, colsumsq, N_GRAPHS);
  k_dgn_final<<<1,640,0,stream>>>(colsum, colsumsq, F[35], F[36], scale, shiftsum, N_GRAPHS);
  k_dgn_apply<<<(N_GRAPHS*64+255)/256,256,0,stream>>>(gout, sbuf, scale, shiftsum, N_GRAPHS);

  // post MLP + head
  k_linear64<64,1,0,0,1><<<NBg,256,0,stream>>>(gout, postWT[0], F[38],      ybuf,  N_GRAPHS);
  k_linear64<64,1,0,0,1><<<NBg,256,0,stream>>>(ybuf, postWT[1], F[38] + 64, ybuf2, N_GRAPHS);
  k_head<<<NBg,256,0,stream>>>(ybuf2, F[39], F[40], (float*)d_out, N_GRAPHS);
}

// Round 6
// 2666.635 us; speedup vs baseline: 3.3119x; 1.0987x over previous
//
#include <hip/hip_runtime.h>
#include <hip/hip_bf16.h>

#define N_NODES 100000
#define N_EDGES 1600000
#define N_GRAPHS 1000
#define HID 64
#define GRP 10

typedef __attribute__((ext_vector_type(8))) short bf16x8;
typedef __attribute__((ext_vector_type(4))) float f32x4;

// ---------- helpers ----------
__device__ __forceinline__ float bf1(unsigned short u){ union{unsigned int x; float f;} v; v.x = ((unsigned int)u)<<16; return v.f; }
__device__ __forceinline__ float bf_lo(unsigned int u){ union{unsigned int x; float f;} v; v.x = u<<16; return v.f; }
__device__ __forceinline__ float bf_hi(unsigned int u){ union{unsigned int x; float f;} v; v.x = u & 0xFFFF0000u; return v.f; }
__device__ __forceinline__ unsigned short f2bf(float f){
  union{float f; unsigned int i;} v; v.f = f;
  unsigned int r = v.i + 0x7FFFu + ((v.i >> 16) & 1u);
  return (unsigned short)(r >> 16);
}
__device__ __forceinline__ float eluf(float v){ return v > 0.f ? v : expm1f(v); }
__device__ __forceinline__ float sigf(float v){ return 1.f/(1.f + expf(-v)); }

// ---------- weight transpose (f32 -> f32) ----------
struct CvtEnt { const float* s; float* d; int rows; int cols; };
struct CvtArgs { CvtEnt e[16]; int cnt; };

__global__ __launch_bounds__(256) void k_convert(CvtArgs a){
  CvtEnt E = a.e[blockIdx.y];
  int n = E.rows * E.cols;
  for (int i = blockIdx.x*256 + threadIdx.x; i < n; i += gridDim.x*256){
    int r = i / E.cols, c = i % E.cols;
    E.d[(size_t)c*E.rows + r] = E.s[i];
  }
}

// ---------- split-bf16 weight prep: dst[n][k] (BT rows), hi/lo pair ----------
struct SpEnt { const float* s; unsigned short* dhi; unsigned short* dlo; int n; int k; int trans; };
struct SpArgs { SpEnt e[12]; int cnt; };

__global__ __launch_bounds__(256) void k_wsplit(SpArgs a){
  SpEnt E = a.e[blockIdx.y];
  int tot = E.n * E.k;
  for (int i = blockIdx.x*256 + threadIdx.x; i < tot; i += gridDim.x*256){
    int nr = i / E.k, kc = i - nr*E.k;
    float v = E.trans ? E.s[(size_t)kc*E.n + nr] : E.s[i];
    unsigned short hi = f2bf(v);
    unsigned short lo = f2bf(v - bf1(hi));
    E.dhi[i] = hi; E.dlo[i] = lo;
  }
}

// bf16 transposed (and K-padded) weights for the MFMA edge-embedding kernel.
__global__ __launch_bounds__(256) void k_wprep(const float* __restrict__ W1,
  const float* __restrict__ W2a, const float* __restrict__ W2b,
  unsigned short* __restrict__ W1Tb, unsigned short* __restrict__ W2Tba,
  unsigned short* __restrict__ W2Tbb)
{
  int i = blockIdx.x*256 + threadIdx.x;   // 0..4095
  if (i >= 4096) return;
  int out = i & 63, k = i >> 6;
  int ks = k < 50 ? k : 0;
  unsigned short v1 = f2bf(W1[ks*64 + out]);
  if (k >= 50) v1 = 0;
  W1Tb [out*64 + k] = v1;
  W2Tba[out*64 + k] = f2bf(W2a[k*64 + out]);
  W2Tbb[out*64 + k] = f2bf(W2b[k*64 + out]);
}

// ---------- CSR build: histogram -> scan -> scatter ----------
__global__ __launch_bounds__(256) void k_hist(const int* __restrict__ dst, int* __restrict__ cnt){
  for (int e = blockIdx.x*256 + threadIdx.x; e < N_EDGES; e += gridDim.x*256)
    atomicAdd(cnt + dst[e], 1);
}

__global__ __launch_bounds__(256) void k_scan1(const int* __restrict__ cnt,
  int* __restrict__ excl, int* __restrict__ bsum, int N)
{
  __shared__ int sh[256];
  int t = threadIdx.x;
  int i = blockIdx.x*256 + t;
  int v = (i < N) ? cnt[i] : 0;
  sh[t] = v;
  __syncthreads();
  #pragma unroll
  for (int o=1;o<256;o<<=1){
    int x = (t>=o) ? sh[t-o] : 0;
    __syncthreads();
    sh[t] += x;
    __syncthreads();
  }
  if (i < N) excl[i] = sh[t] - v;
  if (t == 255) bsum[blockIdx.x] = sh[255];
}

__global__ __launch_bounds__(512) void k_scan2(const int* __restrict__ bsum,
  int* __restrict__ bo, int NB)
{
  __shared__ int sh[512];
  int t = threadIdx.x;
  int v = (t < NB) ? bsum[t] : 0;
  sh[t] = v;
  __syncthreads();
  #pragma unroll
  for (int o=1;o<512;o<<=1){
    int x = (t>=o) ? sh[t-o] : 0;
    __syncthreads();
    sh[t] += x;
    __syncthreads();
  }
  if (t < NB) bo[t] = sh[t] - v;
}

__global__ __launch_bounds__(256) void k_scan3(int* __restrict__ segoff,
  const int* __restrict__ bo, int* __restrict__ cursor, int N)
{
  int i = blockIdx.x*256 + threadIdx.x;
  if (i >= N) return;
  int v = segoff[i] + bo[i>>8];
  segoff[i] = v;
  cursor[i] = v;
  if (i == 0) segoff[N] = N_EDGES;
}

// srcp[pos] = src (scattered); ipos[e] = pos (coalesced inverse perm)
__global__ __launch_bounds__(256) void k_scatter(const int* __restrict__ src,
  const int* __restrict__ dst, int* __restrict__ cursor,
  int* __restrict__ srcp, int* __restrict__ ipos)
{
  for (int e = blockIdx.x*256 + threadIdx.x; e < N_EDGES; e += gridDim.x*256){
    int d = dst[e];
    int pos = atomicAdd(cursor + d, 1);
    srcp[pos] = src[e];
    ipos[e] = pos;
  }
}

// graph segment offsets from sorted batch array
__global__ __launch_bounds__(256) void k_goff(const int* __restrict__ batch, int* __restrict__ goff){
  for (int n = blockIdx.x*256 + threadIdx.x; n < N_NODES; n += gridDim.x*256){
    int b = batch[n];
    int prev = (n==0) ? -1 : batch[n-1];
    for (int g = prev+1; g <= b; g++) goff[g] = n;
    if (n == N_NODES-1){ for (int g=b+1; g<=N_GRAPHS; g++) goff[g] = N_NODES; }
  }
}

// ---------- fused MFMA edge embedding ----------
// Reads edge_attr as a SEQUENTIAL float4 stream (original edge order), computes
// e_emb = relu(EA@W1+b1)@W2, writes each 128B output row to its dst-sorted
// position via ipos (full-line scattered stores, no RMW). Persistent blocks,
// 1-tile-ahead register pipeline.
__global__ __launch_bounds__(256) void k_edge_emb(
  const float* __restrict__ EA, const int* __restrict__ ipos,
  const unsigned short* __restrict__ W1Tb,
  const float* __restrict__ b1, const unsigned short* __restrict__ W2Tb,
  unsigned short* __restrict__ out, int nTiles)
{
  __shared__ float ea[64*50];              // fp32 input tile
  __shared__ unsigned short hb[64*72];     // hidden tile, reused as out staging

  int tid = threadIdx.x;
  int lane = tid & 63;
  int wave = tid >> 6;
  int row16 = lane & 15;
  int kg = lane >> 4;

  // weight fragments hoisted (loaded once per block)
  bf16x8 w1[4][2], w2[4][2];
  #pragma unroll
  for (int n=0;n<4;n++){
    #pragma unroll
    for (int kk=0;kk<2;kk++){
      w1[n][kk] = *(const bf16x8*)(W1Tb + (n*16+row16)*64 + kk*32 + kg*8);
      w2[n][kk] = *(const bf16x8*)(W2Tb + (n*16+row16)*64 + kk*32 + kg*8);
    }
  }
  float bias[4];
  #pragma unroll
  for (int n=0;n<4;n++) bias[n] = b1[n*16+row16];

  int r = wave*16 + row16;
  float4 st[4];

  // prologue: stream-load first tile (800 float4 = 64 rows x 50 f32)
  {
    long t0 = blockIdx.x;
    if (t0 < nTiles){
      const float4* gp = (const float4*)(EA + t0*3200);
      #pragma unroll
      for (int k=0;k<4;k++){
        int j = tid + (k<<8);
        if (j < 800) st[k] = gp[j];
      }
    }
  }

  for (long t = blockIdx.x; t < nTiles; t += gridDim.x){
    // commit staged tile (t) to LDS
    #pragma unroll
    for (int k=0;k<4;k++){
      int j = tid + (k<<8);
      if (j < 800) ((float4*)ea)[j] = st[k];
    }
    __syncthreads();
    // issue stream-load for t+gridDim (overlaps with compute below)
    long tn = t + gridDim.x;
    if (tn < nTiles){
      const float4* gp = (const float4*)(EA + tn*3200);
      #pragma unroll
      for (int k=0;k<4;k++){
        int j = tid + (k<<8);
        if (j < 800) st[k] = gp[j];
      }
    }

    // stage1 A-frags (fp32 -> bf16 in-register)
    bf16x8 a0, a1;
    {
      const float* p = ea + r*50;
      #pragma unroll
      for (int i=0;i<8;i++) ((short*)&a0)[i] = (short)f2bf(p[kg*8+i]);
      #pragma unroll
      for (int i=0;i<8;i++){
        int k = 32 + kg*8 + i;
        ((short*)&a1)[i] = (short)((k < 50) ? f2bf(p[k]) : (unsigned short)0);
      }
    }
    f32x4 c[4];
    #pragma unroll
    for (int n=0;n<4;n++){
      f32x4 acc = {0.f,0.f,0.f,0.f};
      acc = __builtin_amdgcn_mfma_f32_16x16x32_bf16(a0, w1[n][0], acc, 0,0,0);
      acc = __builtin_amdgcn_mfma_f32_16x16x32_bf16(a1, w1[n][1], acc, 0,0,0);
      c[n] = acc;
    }
    // bias + relu, h -> LDS (bf16)
    #pragma unroll
    for (int n=0;n<4;n++){
      #pragma unroll
      for (int q=0;q<4;q++){
        float v = fmaxf(c[n][q] + bias[n], 0.f);
        hb[(wave*16 + kg*4 + q)*72 + n*16 + row16] = f2bf(v);
      }
    }
    __syncthreads();

    // stage2 A-frags from LDS
    bf16x8 ha = *(const bf16x8*)(hb + r*72 + kg*8);
    bf16x8 hc = *(const bf16x8*)(hb + r*72 + 32 + kg*8);
    f32x4 d[4];
    #pragma unroll
    for (int n=0;n<4;n++){
      f32x4 acc = {0.f,0.f,0.f,0.f};
      acc = __builtin_amdgcn_mfma_f32_16x16x32_bf16(ha, w2[n][0], acc, 0,0,0);
      acc = __builtin_amdgcn_mfma_f32_16x16x32_bf16(hc, w2[n][1], acc, 0,0,0);
      d[n] = acc;
    }
    __syncthreads();          // all hb reads done -> reuse as out staging
    #pragma unroll
    for (int n=0;n<4;n++){
      #pragma unroll
      for (int q=0;q<4;q++)
        hb[(wave*16 + kg*4 + q)*72 + n*16 + row16] = f2bf(d[n][q]);
    }
    __syncthreads();

    // scatter store: row rr (128B, one full line) -> sorted position ipos[..]
    {
      int rr = tid >> 2, q = tid & 3;
      int ip = ipos[t*64 + rr];
      const uint4* sp = (const uint4*)(hb + rr*72 + (q<<4));
      uint4 v0 = sp[0], v1 = sp[1];
      uint4* gq = (uint4*)(out + (size_t)ip*64 + (q<<4));
      gq[0] = v0; gq[1] = v1;
    }
  }
}

// ---------- split-bf16 staging helper: write hi/lo 4-short packs ----------
__device__ __forceinline__ void pack4(unsigned short* hi, unsigned short* lo, int ofs,
                                      float v0, float v1, float v2, float v3){
  unsigned short h0=f2bf(v0), h1=f2bf(v1), h2=f2bf(v2), h3=f2bf(v3);
  unsigned short l0=f2bf(v0-bf1(h0)), l1=f2bf(v1-bf1(h1)), l2=f2bf(v2-bf1(h2)), l3=f2bf(v3-bf1(h3));
  uint2 ph, pl;
  ph.x = ((unsigned int)h1<<16)|h0; ph.y = ((unsigned int)h3<<16)|h2;
  pl.x = ((unsigned int)l1<<16)|l0; pl.y = ((unsigned int)l3<<16)|l2;
  *(uint2*)(hi + ofs) = ph;
  *(uint2*)(lo + ofs) = pl;
}

// ---------- MFMA linear (split-bf16, ~fp32 accurate): out = X@W + b, optional dual output ----------
template<int DUAL, int RELU>
__global__ __launch_bounds__(256) void k_lin_mfma(
  const float* __restrict__ X,
  const unsigned short* __restrict__ WAhi, const unsigned short* __restrict__ WAlo,
  const float* __restrict__ bA, float* __restrict__ outA,
  const unsigned short* __restrict__ WBhi, const unsigned short* __restrict__ WBlo,
  const float* __restrict__ bB, float* __restrict__ outB, int N)
{
  __shared__ unsigned short xh[64*72], xlo[64*72];
  int tid = threadIdx.x, lane = tid & 63, wave = tid >> 6;
  int col = lane & 15, kg = lane >> 4;
  long base = (long)blockIdx.x * 64;

  for (int idx = tid; idx < 1024; idx += 256){
    int r = idx >> 4, q = idx & 15;
    long row = base + r;
    float4 v = {0,0,0,0};
    if (row < N) v = ((const float4*)X)[row*16 + q];
    pack4(xh, xlo, r*72 + q*4, v.x, v.y, v.z, v.w);
  }
  __syncthreads();

  int r = wave*16 + col;
  bf16x8 ah[2], al[2];
  ah[0] = *(const bf16x8*)(xh  + r*72 + kg*8);
  ah[1] = *(const bf16x8*)(xh  + r*72 + 32 + kg*8);
  al[0] = *(const bf16x8*)(xlo + r*72 + kg*8);
  al[1] = *(const bf16x8*)(xlo + r*72 + 32 + kg*8);

  #pragma unroll
  for (int ct = 0; ct < 4; ct++){
    f32x4 aA = {0,0,0,0}, aB = {0,0,0,0};
    #pragma unroll
    for (int kk = 0; kk < 2; kk++){
      int wofs = (ct*16 + col)*64 + kk*32 + kg*8;
      bf16x8 bh = *(const bf16x8*)(WAhi + wofs);
      bf16x8 bl = *(const bf16x8*)(WAlo + wofs);
      aA = __builtin_amdgcn_mfma_f32_16x16x32_bf16(ah[kk], bh, aA, 0,0,0);
      aA = __builtin_amdgcn_mfma_f32_16x16x32_bf16(al[kk], bh, aA, 0,0,0);
      aA = __builtin_amdgcn_mfma_f32_16x16x32_bf16(ah[kk], bl, aA, 0,0,0);
      if (DUAL){
        bf16x8 ch = *(const bf16x8*)(WBhi + wofs);
        bf16x8 cl = *(const bf16x8*)(WBlo + wofs);
        aB = __builtin_amdgcn_mfma_f32_16x16x32_bf16(ah[kk], ch, aB, 0,0,0);
        aB = __builtin_amdgcn_mfma_f32_16x16x32_bf16(al[kk], ch, aB, 0,0,0);
        aB = __builtin_amdgcn_mfma_f32_16x16x32_bf16(ah[kk], cl, aB, 0,0,0);
      }
    }
    int c = ct*16 + col;
    float bAv = bA[c];
    float bBv = DUAL ? bB[c] : 0.f;
    #pragma unroll
    for (int reg = 0; reg < 4; reg++){
      long gr = base + wave*16 + kg*4 + reg;
      if (gr < N){
        float vA = aA[reg] + bAv;
        if (RELU) vA = fmaxf(vA, 0.f);
        outA[gr*64 + c] = vA;
        if (DUAL){
          float vB = aB[reg] + bBv;
          if (RELU) vB = fmaxf(vB, 0.f);
          outB[gr*64 + c] = vB;
        }
      }
    }
  }
}

// ---------- MFMA GRU: h = elu(agg+gatb); x = relu(gru(h, x)) in-place ----------
__global__ __launch_bounds__(256) void k_gru_mfma(
  const float* __restrict__ agg, const float* __restrict__ gatb,
  float* __restrict__ x,
  const unsigned short* __restrict__ Wih_hi, const unsigned short* __restrict__ Wih_lo,
  const unsigned short* __restrict__ Whh_hi, const unsigned short* __restrict__ Whh_lo,
  const float* __restrict__ bih, const float* __restrict__ bhh, int N)
{
  __shared__ unsigned short hh_[64*72], hl_[64*72], xh_[64*72], xl_[64*72];
  int tid = threadIdx.x, lane = tid & 63, wave = tid >> 6;
  int col = lane & 15, kg = lane >> 4;
  long base = (long)blockIdx.x * 64;

  for (int idx = tid; idx < 1024; idx += 256){
    int r = idx >> 4, q = idx & 15;
    long row = base + r;
    float4 a = {0,0,0,0}, xx = {0,0,0,0};
    if (row < N){
      a  = ((const float4*)agg)[row*16 + q];
      xx = ((const float4*)x)[row*16 + q];
    }
    float h0 = eluf(a.x + gatb[q*4+0]);
    float h1 = eluf(a.y + gatb[q*4+1]);
    float h2 = eluf(a.z + gatb[q*4+2]);
    float h3 = eluf(a.w + gatb[q*4+3]);
    pack4(hh_, hl_, r*72 + q*4, h0, h1, h2, h3);
    pack4(xh_, xl_, r*72 + q*4, xx.x, xx.y, xx.z, xx.w);
  }
  __syncthreads();

  int r = wave*16 + col;
  bf16x8 hhi[2], hlo[2], xhi[2], xlo2[2];
  hhi[0] = *(const bf16x8*)(hh_ + r*72 + kg*8);
  hhi[1] = *(const bf16x8*)(hh_ + r*72 + 32 + kg*8);
  hlo[0] = *(const bf16x8*)(hl_ + r*72 + kg*8);
  hlo[1] = *(const bf16x8*)(hl_ + r*72 + 32 + kg*8);
  xhi[0] = *(const bf16x8*)(xh_ + r*72 + kg*8);
  xhi[1] = *(const bf16x8*)(xh_ + r*72 + 32 + kg*8);
  xlo2[0] = *(const bf16x8*)(xl_ + r*72 + kg*8);
  xlo2[1] = *(const bf16x8*)(xl_ + r*72 + 32 + kg*8);

  #pragma unroll
  for (int ct = 0; ct < 4; ct++){
    f32x4 ai[3], ah[3];
    #pragma unroll
    for (int g=0; g<3; g++){ ai[g] = (f32x4){0,0,0,0}; ah[g] = (f32x4){0,0,0,0}; }
    #pragma unroll
    for (int g = 0; g < 3; g++){
      int nt = g*4 + ct;
      #pragma unroll
      for (int kk = 0; kk < 2; kk++){
        int wofs = (nt*16 + col)*64 + kk*32 + kg*8;
        bf16x8 bh = *(const bf16x8*)(Wih_hi + wofs);
        bf16x8 bl = *(const bf16x8*)(Wih_lo + wofs);
        ai[g] = __builtin_amdgcn_mfma_f32_16x16x32_bf16(hhi[kk], bh, ai[g], 0,0,0);
        ai[g] = __builtin_amdgcn_mfma_f32_16x16x32_bf16(hlo[kk], bh, ai[g], 0,0,0);
        ai[g] = __builtin_amdgcn_mfma_f32_16x16x32_bf16(hhi[kk], bl, ai[g], 0,0,0);
        bf16x8 ch = *(const bf16x8*)(Whh_hi + wofs);
        bf16x8 cl = *(const bf16x8*)(Whh_lo + wofs);
        ah[g] = __builtin_amdgcn_mfma_f32_16x16x32_bf16(xhi[kk], ch, ah[g], 0,0,0);
        ah[g] = __builtin_amdgcn_mfma_f32_16x16x32_bf16(xlo2[kk], ch, ah[g], 0,0,0);
        ah[g] = __builtin_amdgcn_mfma_f32_16x16x32_bf16(xhi[kk], cl, ah[g], 0,0,0);
      }
    }
    int c = ct*16 + col;
    float bi0 = bih[c], bi1 = bih[64+c], bi2 = bih[128+c];
    float bh0 = bhh[c], bh1 = bhh[64+c], bh2 = bhh[128+c];
    #pragma unroll
    for (int reg = 0; reg < 4; reg++){
      int rr = wave*16 + kg*4 + reg;
      long gr = base + rr;
      float ir = ai[0][reg] + bi0, iz = ai[1][reg] + bi1, in2 = ai[2][reg] + bi2;
      float hr = ah[0][reg] + bh0, hz = ah[1][reg] + bh1, hn = ah[2][reg] + bh2;
      float xv = bf1(xh_[rr*72 + c]) + bf1(xl_[rr*72 + c]);
      float r_ = sigf(ir + hr);
      float z  = sigf(iz + hz);
      float nn = tanhf(in2 + r_*hn);
      float o = (1.f - z)*nn + z*xv;
      if (gr < N) x[gr*64 + c] = fmaxf(o, 0.f);
    }
  }
}

// ---------- generic linear: out[n,0..63] = act(A[n,:] @ W + b) ----------
template<int K, int RELU, int INBF, int OUTBF, int HASB>
__global__ __launch_bounds__(256) void k_linear64(const void* Ap,
    const float* __restrict__ WT, const float* __restrict__ bias, void* Op, int N)
{
  int n = blockIdx.x*256 + threadIdx.x;
  if (n >= N) return;
  float a[K];
  if constexpr (INBF){
    const unsigned int* p = (const unsigned int*)((const unsigned short*)Ap + (size_t)n*K);
    #pragma unroll
    for (int i=0;i<K/2;i++){ unsigned int u=p[i]; a[2*i]=bf_lo(u); a[2*i+1]=bf_hi(u); }
  } else if constexpr (K % 4 == 0){
    const float4* p = (const float4*)((const float*)Ap + (size_t)n*K);
    #pragma unroll
    for (int i=0;i<K/4;i++){ float4 v=p[i]; a[4*i]=v.x; a[4*i+1]=v.y; a[4*i+2]=v.z; a[4*i+3]=v.w; }
  } else {
    const float2* p = (const float2*)((const float*)Ap + (size_t)n*K);
    #pragma unroll
    for (int i=0;i<K/2;i++){ float2 v=p[i]; a[2*i]=v.x; a[2*i+1]=v.y; }
  }
  for (int c=0;c<64;c+=4){
    float s0 = HASB ? bias[c+0] : 0.f;
    float s1 = HASB ? bias[c+1] : 0.f;
    float s2 = HASB ? bias[c+2] : 0.f;
    float s3 = HASB ? bias[c+3] : 0.f;
    const float* w = WT + (size_t)c*K;
    #pragma unroll
    for (int k=0;k<K;k++){
      float av = a[k];
      s0 = fmaf(av, w[k],     s0);
      s1 = fmaf(av, w[K+k],   s1);
      s2 = fmaf(av, w[2*K+k], s2);
      s3 = fmaf(av, w[3*K+k], s3);
    }
    if (RELU){ s0=fmaxf(s0,0.f); s1=fmaxf(s1,0.f); s2=fmaxf(s2,0.f); s3=fmaxf(s3,0.f); }
    if constexpr (OUTBF){
      uint2 uu;
      uu.x = ((unsigned int)f2bf(s1)<<16) | f2bf(s0);
      uu.y = ((unsigned int)f2bf(s3)<<16) | f2bf(s2);
      *(uint2*)((unsigned short*)Op + (size_t)n*64 + c) = uu;
    } else {
      float4 r; r.x=s0; r.y=s1; r.z=s2; r.w=s3;
      *(float4*)((float*)Op + (size_t)n*64 + c) = r;
    }
  }
}

// ---------- fused GATv2 attention+aggregate ----------
// 16 lanes per edge (lane sq owns channels 4sq..4sq+3), 4 edges per wave
// iteration. Dot-reduce = 4 shuffle steps over 16 lanes for 4 edges at once;
// per-group online-softmax states merged once per segment (exact math).
template<int HASEMB, int IDSRC>
__global__ __launch_bounds__(256) void k_gat_fused(
  const int* __restrict__ srcp, const int* __restrict__ segoff,
  const float* __restrict__ xl, const float* __restrict__ xr,
  const unsigned short* __restrict__ emb, const float* __restrict__ att,
  float* __restrict__ agg, int nseg)
{
  int lane = threadIdx.x & 63;
  int grp = lane >> 4;        // edge slot within quad
  int sq  = lane & 15;        // channel quad
  float4 av = ((const float4*)att)[sq];
  int wid = (blockIdx.x*256 + threadIdx.x) >> 6;
  int nw  = (gridDim.x*256) >> 6;
  for (int d = wid; d < nseg; d += nw){
    int e0 = segoff[d], e1 = segoff[d+1];
    float4 xrv = ((const float4*)(xr + (size_t)d*64))[sq];
    float m = -3.0e38f, s = 0.f;
    float4 acc = {0.f,0.f,0.f,0.f};
    for (int eb = e0; eb < e1; eb += 4){
      int e = eb + grp;
      bool act = e < e1;
      int ee = act ? e : e0;
      int sN = IDSRC ? ee : srcp[ee];
      float4 xs = ((const float4*)(xl + (size_t)sN*64))[sq];
      float4 v;
      v.x = xs.x + xrv.x; v.y = xs.y + xrv.y;
      v.z = xs.z + xrv.z; v.w = xs.w + xrv.w;
      if (HASEMB){
        uint2 u = *(const uint2*)(emb + (size_t)ee*64 + (sq<<2));
        v.x += bf_lo(u.x); v.y += bf_hi(u.x);
        v.z += bf_lo(u.y); v.w += bf_hi(u.y);
      }
      v.x = v.x > 0.f ? v.x : 0.01f*v.x;
      v.y = v.y > 0.f ? v.y : 0.01f*v.y;
      v.z = v.z > 0.f ? v.z : 0.01f*v.z;
      v.w = v.w > 0.f ? v.w : 0.01f*v.w;
      float p = v.x*av.x;
      p = fmaf(v.y, av.y, p);
      p = fmaf(v.z, av.z, p);
      p = fmaf(v.w, av.w, p);
      p += __shfl_xor(p, 1, 64);
      p += __shfl_xor(p, 2, 64);
      p += __shfl_xor(p, 4, 64);
      p += __shfl_xor(p, 8, 64);
      if (!act) p = -3.0e38f;
      float mn = fmaxf(m, p);
      float cm = expf(m - mn);
      float cp = act ? expf(p - mn) : 0.f;
      s = fmaf(s, cm, cp);
      acc.x = fmaf(acc.x, cm, cp*xs.x);
      acc.y = fmaf(acc.y, cm, cp*xs.y);
      acc.z = fmaf(acc.z, cm, cp*xs.z);
      acc.w = fmaf(acc.w, cm, cp*xs.w);
      m = mn;
    }
    // merge the 4 per-group online states (butterfly over grp bits: xor 16, 32)
    float mo = fmaxf(m, __shfl_xor(m, 16, 64));
    float M  = fmaxf(mo, __shfl_xor(mo, 32, 64));
    float w  = expf(m - M);
    s *= w; acc.x *= w; acc.y *= w; acc.z *= w; acc.w *= w;
    s += __shfl_xor(s, 16, 64);  s += __shfl_xor(s, 32, 64);
    acc.x += __shfl_xor(acc.x, 16, 64); acc.x += __shfl_xor(acc.x, 32, 64);
    acc.y += __shfl_xor(acc.y, 16, 64); acc.y += __shfl_xor(acc.y, 32, 64);
    acc.z += __shfl_xor(acc.z, 16, 64); acc.z += __shfl_xor(acc.z, 32, 64);
    acc.w += __shfl_xor(acc.w, 16, 64); acc.w += __shfl_xor(acc.w, 32, 64);
    if (grp == 0){
      float inv = 1.f/(s + 1e-16f);
      float4 o;
      o.x = acc.x*inv; o.y = acc.y*inv; o.z = acc.z*inv; o.w = acc.w*inv;
      ((float4*)(agg + (size_t)d*64))[sq] = o;
    }
  }
}

// ---------- DiffGroupNorm ----------
__global__ __launch_bounds__(256) void k_dgn_s(const float* __restrict__ x,
  const float* __restrict__ WT /*10x64*/, const float* __restrict__ b,
  float* __restrict__ s, int N)
{
  int n = blockIdx.x*256 + threadIdx.x;
  if (n >= N) return;
  float a[64];
  const float4* p = (const float4*)(x + (size_t)n*64);
  #pragma unroll
  for (int i=0;i<16;i++){ float4 v=p[i]; a[4*i]=v.x; a[4*i+1]=v.y; a[4*i+2]=v.z; a[4*i+3]=v.w; }
  float lg[10];
  #pragma unroll
  for (int g=0; g<10; g++){
    float acc = b[g];
    const float* w = WT + (size_t)g*64;
    #pragma unroll
    for (int k=0;k<64;k++) acc = fmaf(a[k], w[k], acc);
    lg[g] = acc;
  }
  float m = lg[0];
  #pragma unroll
  for (int g=1;g<10;g++) m = fmaxf(m, lg[g]);
  float e[10], sum = 0.f;
  #pragma unroll
  for (int g=0;g<10;g++){ e[g] = expf(lg[g]-m); sum += e[g]; }
  float inv = 1.f/sum;
  #pragma unroll
  for (int g=0;g<10;g++) s[(size_t)n*10+g] = e[g]*inv;
}

__global__ __launch_bounds__(640) void k_dgn_stats(const float* __restrict__ s,
  const float* __restrict__ x, float* cs, float* cs2, int N)
{
  int g = threadIdx.x >> 6, f = threadIdx.x & 63;
  int per = (N + gridDim.x - 1) / gridDim.x;
  int n0 = blockIdx.x * per;
  int n1 = min(N, n0 + per);
  float a = 0.f, a2 = 0.f;
  for (int n = n0; n < n1; n++){
    float y = s[(size_t)n*10+g] * x[(size_t)n*64+f];
    a += y; a2 += y*y;
  }
  atomicAdd(&cs [g*64+f], a);
  atomicAdd(&cs2[g*64+f], a2);
}

__global__ void k_dgn_final(const float* cs, const float* cs2,
  const float* __restrict__ bw, const float* __restrict__ bb,
  float* scale, float* shiftsum, int N)
{
  __shared__ float sh[640];
  int i = threadIdx.x;
  float invN = 1.f / (float)N;
  float mean = cs[i]*invN;
  float var  = cs2[i]*invN - mean*mean;
  float sc = bw[i] / sqrtf(var + 1e-5f);
  scale[i] = sc;
  sh[i] = bb[i] - mean*sc;
  __syncthreads();
  if (i < 64){
    float t = 0.f;
    #pragma unroll
    for (int g=0;g<10;g++) t += sh[g*64+i];
    shiftsum[i] = t;
  }
}

__global__ __launch_bounds__(256) void k_dgn_apply(float* x,
  const float* __restrict__ s, const float* __restrict__ scale,
  const float* __restrict__ shiftsum, int N)
{
  int idx = blockIdx.x*256 + threadIdx.x;
  if (idx >= N*64) return;
  int n = idx >> 6, f = idx & 63;
  float ss = 0.f;
  #pragma unroll
  for (int g=0; g<10; g++) ss = fmaf(s[(size_t)n*10+g], scale[g*64+f], ss);
  float xvv = x[idx];
  x[idx] = xvv + 0.01f*(xvv*ss + shiftsum[f]);
}

// ---------- readout: pull-based segment sum + relu ----------
__global__ __launch_bounds__(256) void k_gseg(const float* __restrict__ x,
  const int* __restrict__ goff, float* __restrict__ gout)
{
  int lane = threadIdx.x & 63;
  int wid = (blockIdx.x*256 + threadIdx.x) >> 6;
  int nw  = (gridDim.x*256) >> 6;
  for (int g = wid; g < N_GRAPHS; g += nw){
    int n0 = goff[g], n1 = goff[g+1];
    float acc = 0.f;
    for (int n = n0; n < n1; n++) acc += x[(size_t)n*64 + lane];
    gout[(size_t)g*64 + lane] = fmaxf(acc, 0.f);
  }
}

__global__ __launch_bounds__(256) void k_head(const float* __restrict__ y,
  const float* __restrict__ w, const float* __restrict__ b,
  float* __restrict__ out, int N)
{
  int n = blockIdx.x*256 + threadIdx.x;
  if (n >= N) return;
  float acc = b[0];
  const float4* p = (const float4*)(y + (size_t)n*64);
  #pragma unroll
  for (int i=0;i<16;i++){
    float4 v = p[i];
    acc = fmaf(v.x, w[4*i+0], acc);
    acc = fmaf(v.y, w[4*i+1], acc);
    acc = fmaf(v.z, w[4*i+2], acc);
    acc = fmaf(v.w, w[4*i+3], acc);
  }
  out[n] = acc;
}

// ---------- host ----------
extern "C" void kernel_launch(void* const* d_in, const int* in_sizes, int n_in,
                              void* d_out, int out_size, void* d_ws, size_t ws_size,
                              hipStream_t stream) {
  (void)in_sizes; (void)n_in; (void)out_size; (void)ws_size;

  // ----- workspace layout -----
  char* base = (char*)d_ws; size_t off = 0;
  auto A = [&](size_t bytes)->void*{ void* p = base + off; off += (bytes + 255) & ~(size_t)255; return p; };
  unsigned short* e_emb = (unsigned short*)A((size_t)N_EDGES*64*2);   // bf16 e_emb (dst-sorted order)
  float* xbuf   = (float*)A((size_t)N_NODES*64*4);
  float* xl     = (float*)A((size_t)N_NODES*64*4);
  float* xr     = (float*)A((size_t)N_NODES*64*4);
  float* agg    = (float*)A((size_t)N_NODES*64*4);
  int*   ipos   = (int*)A((size_t)N_EDGES*4);
  int*   srcp   = (int*)A((size_t)N_EDGES*4);
  int*   segoff = (int*)A((size_t)(N_NODES+1)*4);
  int*   cursor = (int*)A((size_t)N_NODES*4);
  int*   bsum   = (int*)A(512*4);
  int*   bo     = (int*)A(512*4);
  int*   goff   = (int*)A((size_t)(N_GRAPHS+1)*4);
  float* sbuf   = (float*)A((size_t)N_NODES*10*4);
  float* gout   = (float*)A((size_t)N_GRAPHS*64*4);
  float* ybuf   = (float*)A((size_t)N_GRAPHS*64*4);
  float* ybuf2  = (float*)A((size_t)N_GRAPHS*64*4);
  float* colsum = (float*)A(2*640*4); float* colsumsq = colsum + 640;
  float* scale  = (float*)A((640+64)*4); float* shiftsum = scale + 640;
  unsigned short* W1Tb  = (unsigned short*)A(4096*2);
  unsigned short* W2Tb0 = (unsigned short*)A(4096*2);
  unsigned short* W2Tb1 = (unsigned short*)A(4096*2);
  // split-bf16 weights: lin (BT rows 64x64): Wl0,Wl1,Wr0,Wr1,gWl
  unsigned short* LHI[5]; unsigned short* LLO[5];
  for (int i=0;i<5;i++){ LHI[i]=(unsigned short*)A(4096*2); LLO[i]=(unsigned short*)A(4096*2); }
  // split-bf16 GRU weights ([192][64]): ih0,ih1,hh0,hh1,gih,ghh
  unsigned short* GHI[6]; unsigned short* GLO[6];
  for (int i=0;i<6;i++){ GHI[i]=(unsigned short*)A(12288*2); GLO[i]=(unsigned short*)A(12288*2); }
  float* wf     = (float*)A(60000*4);
  size_t wo = 0;
  auto W = [&](size_t n)->float*{ float* p = wf + wo; wo += n; return p; };

  float* pre_nWT = W(64*92);
  float* gnWT[2] = {W(640), W(640)};
  float* gWrT = W(4096);
  float* ggnWT = W(640);
  float* postWT[2] = {W(4096), W(4096)};

  const float* F[48];
  for (int i=0;i<41;i++) F[i] = (const float*)d_in[i];

  // ----- transpose table (fp32 weights still used by scalar kernels) -----
  CvtArgs ca; ca.cnt = 0;
  auto addT = [&](const float* s, float* d, int r, int c){
    ca.e[ca.cnt].s=s; ca.e[ca.cnt].d=d; ca.e[ca.cnt].rows=r; ca.e[ca.cnt].cols=c; ca.cnt++; };

  addT(F[4],  pre_nWT, 92, 64);
  for (int l=0;l<2;l++) addT(F[19] + l*640,  gnWT[l], 64, 10);
  addT(F[25], gWrT, 64, 64);
  addT(F[33], ggnWT, 64, 10);
  for (int l=0;l<2;l++) addT(F[37] + l*4096, postWT[l], 64, 64);

  // ----- split-bf16 table -----
  SpArgs sa; sa.cnt = 0;
  auto addS = [&](const float* s, unsigned short* dhi, unsigned short* dlo, int n, int k, int tr){
    sa.e[sa.cnt].s=s; sa.e[sa.cnt].dhi=dhi; sa.e[sa.cnt].dlo=dlo;
    sa.e[sa.cnt].n=n; sa.e[sa.cnt].k=k; sa.e[sa.cnt].trans=tr; sa.cnt++; };
  for (int l=0;l<2;l++) addS(F[8]  + l*4096, LHI[l],   LLO[l],   64, 64, 1);  // Wl
  for (int l=0;l<2;l++) addS(F[10] + l*4096, LHI[2+l], LLO[2+l], 64, 64, 1);  // Wr
  addS(F[23], LHI[4], LLO[4], 64, 64, 1);                                     // gWl
  for (int l=0;l<2;l++) addS(F[15] + l*12288, GHI[l],   GLO[l],   192, 64, 0); // Wih
  for (int l=0;l<2;l++) addS(F[16] + l*12288, GHI[2+l], GLO[2+l], 192, 64, 0); // Whh
  addS(F[29], GHI[4], GLO[4], 192, 64, 0);                                    // gWih
  addS(F[30], GHI[5], GLO[5], 192, 64, 0);                                    // gWhh

  const int* src   = (const int*)d_in[1];
  const int* dst   = src + N_EDGES;
  const int* batch = (const int*)d_in[3];

  const int NBn = (N_NODES + 255)/256;    // 391
  const int NBg = (N_GRAPHS + 255)/256;   // 4
  const int NBa = (N_NODES*64)/256;       // 25000
  const int NTIL = N_EDGES/64;            // 25000 tiles
  const int NBt = (N_NODES + 63)/64;      // 1563 (64-row MFMA tiles)
  const int NBtg = (N_GRAPHS + 63)/64;    // 16

  k_convert<<<dim3(24, ca.cnt), 256, 0, stream>>>(ca);
  k_wsplit<<<dim3(8, sa.cnt), 256, 0, stream>>>(sa);
  k_wprep<<<16,256,0,stream>>>(F[6], F[12], F[12]+4096, W1Tb, W2Tb0, W2Tb1);

  // ----- CSR build (dst-sorted edge list), once per launch -----
  hipMemsetAsync(cursor, 0, (size_t)N_NODES*4, stream);
  k_hist<<<2048,256,0,stream>>>(dst, cursor);
  k_scan1<<<NBn,256,0,stream>>>(cursor, segoff, bsum, N_NODES);
  k_scan2<<<1,512,0,stream>>>(bsum, bo, NBn);
  k_scan3<<<NBn,256,0,stream>>>(segoff, bo, cursor, N_NODES);
  k_scatter<<<2048,256,0,stream>>>(src, dst, cursor, srcp, ipos);
  k_goff<<<NBn,256,0,stream>>>(batch, goff);

  // x = relu(x_in @ pre_nW + pre_nb)
  k_linear64<92,1,0,0,1><<<NBn,256,0,stream>>>(F[0], pre_nWT, F[5], xbuf, N_NODES);

  for (int l=0; l<2; l++){
    // e_emb = relu(edge_attr @ pre_eW + pre_eb) @ We[l]  (stream in, scatter out)
    k_edge_emb<<<4096,256,0,stream>>>(F[2], ipos, W1Tb, F[7], (l==0)?W2Tb0:W2Tb1, e_emb, NTIL);

    for (int t=0; t<2; t++){
      // xl, xr in one fused MFMA pass
      k_lin_mfma<1,0><<<NBt,256,0,stream>>>(xbuf,
          LHI[l], LLO[l], F[9] + l*64, xl,
          LHI[2+l], LLO[2+l], F[11] + l*64, xr, N_NODES);
      k_gat_fused<1,0><<<4096,256,0,stream>>>(srcp, segoff, xl, xr, e_emb,
                                              F[13] + l*64, agg, N_NODES);
      k_gru_mfma<<<NBt,256,0,stream>>>(agg, F[14] + l*64, xbuf,
          GHI[l], GLO[l], GHI[2+l], GLO[2+l],
          F[17] + l*192, F[18] + l*192, N_NODES);
    }
    hipMemsetAsync(colsum, 0, 2*640*4, stream);
    k_dgn_s<<<NBn,256,0,stream>>>(xbuf, gnWT[l], F[20] + l*10, sbuf, N_NODES);
    k_dgn_stats<<<512,640,0,stream>>>(sbuf, xbuf, colsum, colsumsq, N_NODES);
    k_dgn_final<<<1,640,0,stream>>>(colsum, colsumsq, F[21] + l*640, F[22] + l*640, scale, shiftsum, N_NODES);
    k_dgn_apply<<<NBa,256,0,stream>>>(xbuf, sbuf, scale, shiftsum, N_NODES);
  }

  // readout: out = relu(segment_sum(x, batch))  (pull-based, no atomics)
  k_gseg<<<250,256,0,stream>>>(xbuf, goff, gout);

  // xl_g fixed across both timesteps (x doesn't change here)
  k_lin_mfma<0,0><<<NBt,256,0,stream>>>(xbuf, LHI[4], LLO[4], F[24], xl,
                                        nullptr, nullptr, nullptr, nullptr, N_NODES);
  for (int t=0; t<2; t++){
    k_linear64<64,0,0,0,1><<<NBg,256,0,stream>>>(gout, gWrT, F[26], xr, N_GRAPHS);
    k_gat_fused<0,1><<<256,256,0,stream>>>(nullptr, goff, xl, xr, nullptr,
                                           F[27], agg, N_GRAPHS);
    k_gru_mfma<<<NBtg,256,0,stream>>>(agg, F[28], gout,
        GHI[4], GLO[4], GHI[5], GLO[5], F[31], F[32], N_GRAPHS);
  }

  hipMemsetAsync(colsum, 0, 2*640*4, stream);
  k_dgn_s<<<NBg,256,0,stream>>>(gout, ggnWT, F[34], sbuf, N_GRAPHS);
  k_dgn_stats<<<8,640,0,stream>>>(sbuf, gout, colsum, colsumsq, N_GRAPHS);
  k_dgn_final<<<1,640,0,stream>>>(colsum, colsumsq, F[35], F[36], scale, shiftsum, N_GRAPHS);
  k_dgn_apply<<<(N_GRAPHS*64+255)/256,256,0,stream>>>(gout, sbuf, scale, shiftsum, N_GRAPHS);

  // post MLP + head
  k_linear64<64,1,0,0,1><<<NBg,256,0,stream>>>(gout, postWT[0], F[38],      ybuf,  N_GRAPHS);
  k_linear64<64,1,0,0,1><<<NBg,256,0,stream>>>(ybuf, postWT[1], F[38] + 64, ybuf2, N_GRAPHS);
  k_head<<<NBg,256,0,stream>>>(ybuf2, F[39], F[40], (float*)d_out, N_GRAPHS);
}